// Round 4
// baseline (234029.126 us; speedup 1.0000x reference)
//
#include <hip/hip_runtime.h>
#include <cstdint>

typedef unsigned short ushortT;
typedef __attribute__((ext_vector_type(8))) short s8v;   // 8 bf16 (4 VGPRs)
typedef __attribute__((ext_vector_type(4))) float f4v;   // MFMA acc

#define B_  32
#define TIN 400
#define TOUT 500

// ---------------- threefry2x32 (JAX, 20 rounds) ----------------
__host__ __device__ __forceinline__ uint32_t rotl32(uint32_t v, int r){ return (v<<r)|(v>>(32-r)); }
__host__ __device__ inline void tf2x32(uint32_t k0, uint32_t k1, uint32_t x0, uint32_t x1,
                                       uint32_t* o0, uint32_t* o1){
  uint32_t ks2 = k0 ^ k1 ^ 0x1BD11BDAu;
  x0 += k0; x1 += k1;
  x0+=x1; x1=rotl32(x1,13); x1^=x0;  x0+=x1; x1=rotl32(x1,15); x1^=x0;
  x0+=x1; x1=rotl32(x1,26); x1^=x0;  x0+=x1; x1=rotl32(x1, 6); x1^=x0;
  x0+=k1; x1+=ks2+1u;
  x0+=x1; x1=rotl32(x1,17); x1^=x0;  x0+=x1; x1=rotl32(x1,29); x1^=x0;
  x0+=x1; x1=rotl32(x1,16); x1^=x0;  x0+=x1; x1=rotl32(x1,24); x1^=x0;
  x0+=ks2; x1+=k0+2u;
  x0+=x1; x1=rotl32(x1,13); x1^=x0;  x0+=x1; x1=rotl32(x1,15); x1^=x0;
  x0+=x1; x1=rotl32(x1,26); x1^=x0;  x0+=x1; x1=rotl32(x1, 6); x1^=x0;
  x0+=k0; x1+=k1+3u;
  x0+=x1; x1=rotl32(x1,17); x1^=x0;  x0+=x1; x1=rotl32(x1,29); x1^=x0;
  x0+=x1; x1=rotl32(x1,16); x1^=x0;  x0+=x1; x1=rotl32(x1,24); x1^=x0;
  x0+=k1; x1+=ks2+4u;
  x0+=x1; x1=rotl32(x1,13); x1^=x0;  x0+=x1; x1=rotl32(x1,15); x1^=x0;
  x0+=x1; x1=rotl32(x1,26); x1^=x0;  x0+=x1; x1=rotl32(x1, 6); x1^=x0;
  x0+=ks2; x1+=k0+5u;
  *o0 = x0; *o1 = x1;
}
// JAX partitionable random_bits (32-bit): counter = (0, i), fold = o0 ^ o1
__device__ __forceinline__ float part_unif(uint32_t ka, uint32_t kb, uint32_t idx){
  uint32_t o0,o1; tf2x32(ka,kb,0u,idx,&o0,&o1);
  uint32_t bits = o0 ^ o1;
  return __uint_as_float(0x3f800000u | (bits>>9)) - 1.0f;
}

// ---------------- helpers ----------------
__device__ __forceinline__ float bf2f(ushortT u){ return __uint_as_float(((uint32_t)u)<<16); }
__device__ __forceinline__ ushortT f2bf(float f){
  uint32_t x = __float_as_uint(f);
  return (ushortT)((x + 0x7fffu + ((x>>16)&1u)) >> 16);
}
__device__ __forceinline__ float sigm(float x){ return 1.0f/(1.0f+__expf(-x)); }
__device__ __forceinline__ f4v mfma16(s8v a, s8v b, f4v c){
  return __builtin_amdgcn_mfma_f32_16x16x32_bf16(a,b,c,0,0,0);
}
__device__ __forceinline__ s8v pack8(const float* p){
  s8v r;
  #pragma unroll
  for (int j=0;j<8;++j) r[j]=(short)f2bf(p[j]);
  return r;
}

// ---------------- LDS union ----------------
struct SmemB1{ float awp[130],awcp[130],cw0[992],cw1[992],vv[128],pqv[128],epart[200]; float lw[4224]; float locl[3200]; };
struct SmemL { float gbuf[4][32][17]; float qsl[128*17]; float ahs[32*17]; };
struct SmemB2{ float p[400]; float red[8]; float part[256]; };
struct SmemPj{ float dsum[2][32][16]; };
union SmemU{ SmemB1 b1; SmemL l; SmemB2 b2; SmemPj pj; };

// ---------------- grid barrier (manual, graph-capture safe) ----------------
__device__ __forceinline__ void gridbar(int* bar, int tgt){
  __syncthreads();                                // drains vmcnt for all waves
  if (threadIdx.x==0){
    __threadfence();                              // release: wb L2 to device scope
    __hip_atomic_fetch_add(bar, 1, __ATOMIC_RELEASE, __HIP_MEMORY_SCOPE_AGENT);
    while (__hip_atomic_load(bar, __ATOMIC_ACQUIRE, __HIP_MEMORY_SCOPE_AGENT) < tgt)
      __builtin_amdgcn_s_sleep(4);
    __threadfence();                              // acquire: invalidate stale L1/L2
  }
  __syncthreads();
}

// ---------------- setup ----------------
__global__ __launch_bounds__(256) void k_setup(
  const float* __restrict__ awih, const float* __restrict__ awhh,
  const float* __restrict__ dwih, const float* __restrict__ dwhh,
  const float* __restrict__ pjw,  const float* __restrict__ gw,
  const float* __restrict__ memory, const float* __restrict__ qw,
  ushortT* __restrict__ Wai, ushortT* __restrict__ Wah,
  ushortT* __restrict__ Wdi, ushortT* __restrict__ Wdh,
  ushortT* __restrict__ Wpg, ushortT* __restrict__ memB, ushortT* __restrict__ qwB,
  ushortT* __restrict__ AH0, ushortT* __restrict__ AH1,
  ushortT* __restrict__ DH0, ushortT* __restrict__ DH1,
  ushortT* __restrict__ CTX,
  float* __restrict__ ac, float* __restrict__ dc,
  float* __restrict__ aw, float* __restrict__ awc,
  float* __restrict__ pq, int* __restrict__ bar)
{
  int stride = gridDim.x*blockDim.x;
  int g0 = blockIdx.x*blockDim.x + threadIdx.x;
  for (int i=g0; i<4096*768;  i+=stride) Wai[i]=f2bf(awih[i]);
  for (int i=g0; i<4096*1024; i+=stride) Wah[i]=f2bf(awhh[i]);
  for (int i=g0; i<4096*1536; i+=stride) Wdi[i]=f2bf(dwih[i]);
  for (int i=g0; i<4096*1024; i+=stride) Wdh[i]=f2bf(dwhh[i]);
  for (int i=g0; i<32*400*512; i+=stride) memB[i]=f2bf(memory[i]);
  for (int i=g0; i<128*1024; i+=stride) qwB[i]=f2bf(qw[i]);
  for (int i=g0; i<96*1536; i+=stride){
    int r=i/1536, k=i-r*1536;
    ushortT v=0;
    if (r<80) v=f2bf(pjw[r*1536+k]);
    else if (r==80) v=f2bf(gw[k]);
    Wpg[i]=v;
  }
  for (int i=g0; i<32*1024; i+=stride){ ac[i]=0.f; dc[i]=0.f; AH0[i]=0; AH1[i]=0; DH0[i]=0; DH1[i]=0; }
  for (int i=g0; i<32*512;  i+=stride){ CTX[i]=0; }
  for (int i=g0; i<32*400;  i+=stride){ aw[i]=0.f; awc[i]=0.f; }
  for (int i=g0; i<32*128;  i+=stride){ pq[i]=0.f; }
  if (g0 < 64) bar[g0]=0;
}

// ---------------- fused prenet (unchanged, verified) ----------------
__global__ __launch_bounds__(256) void k_prenet(
  const float* __restrict__ dec_inp, const float* __restrict__ w1, const float* __restrict__ w2,
  ushortT* __restrict__ preo,
  uint32_t k1a, uint32_t k1b, uint32_t k2a, uint32_t k2b)
{
  __shared__ ushortT Xs[64*96];
  __shared__ ushortT H1s[64*256];
  int tid=threadIdx.x, lane=tid&63, wv=tid>>6, quad=lane>>4, nl=lane&15;
  int r0 = blockIdx.x*64;
  for (int i=tid; i<64*96; i+=256){
    int rr=i/96, k=i-rr*96; int row=r0+rr; int s=row>>5, b=row&31;
    float v=0.f;
    if (k<80 && s>0) v = dec_inp[((size_t)b*80+k)*500 + (s-1)];
    Xs[i]=f2bf(v);
  }
  __syncthreads();
  f4v acc[4][4];
  #pragma unroll
  for (int mt=0;mt<4;++mt)
    #pragma unroll
    for (int nt=0;nt<4;++nt) acc[mt][nt]=(f4v){0,0,0,0};
  for (int kb=0;kb<3;++kb){
    int c0 = kb*32 + quad*8;
    s8v a[4];
    #pragma unroll
    for (int mt=0;mt<4;++mt) a[mt]=*(const s8v*)(Xs + (mt*16+nl)*96 + c0);
    #pragma unroll
    for (int nt=0;nt<4;++nt){
      int rown = wv*64+nt*16+nl;
      s8v bb;
      if (c0 < 80) bb = pack8(w1 + (size_t)rown*80 + c0);
      else { s8v z={0,0,0,0,0,0,0,0}; bb=z; }
      #pragma unroll
      for (int mt=0;mt<4;++mt) acc[mt][nt]=mfma16(a[mt],bb,acc[mt][nt]);
    }
  }
  #pragma unroll
  for (int mt=0;mt<4;++mt)
    #pragma unroll
    for (int nt=0;nt<4;++nt)
      #pragma unroll
      for (int r=0;r<4;++r){
        int mloc = mt*16+quad*4+r;
        int col  = wv*64+nt*16+nl;
        float v = acc[mt][nt][r]; v = v>0.f? v:0.f;
        uint32_t fidx = (uint32_t)(r0+mloc)*256u + (uint32_t)col;
        v = (part_unif(k1a,k1b,fidx) < 0.5f) ? v*2.0f : 0.0f;
        H1s[mloc*256+col]=f2bf(v);
      }
  __syncthreads();
  #pragma unroll
  for (int mt=0;mt<4;++mt)
    #pragma unroll
    for (int nt=0;nt<4;++nt) acc[mt][nt]=(f4v){0,0,0,0};
  for (int kb=0;kb<8;++kb){
    int c0 = kb*32 + quad*8;
    s8v a[4];
    #pragma unroll
    for (int mt=0;mt<4;++mt) a[mt]=*(const s8v*)(H1s + (mt*16+nl)*256 + c0);
    #pragma unroll
    for (int nt=0;nt<4;++nt){
      int rown = wv*64+nt*16+nl;
      s8v bb = pack8(w2 + (size_t)rown*256 + c0);
      #pragma unroll
      for (int mt=0;mt<4;++mt) acc[mt][nt]=mfma16(a[mt],bb,acc[mt][nt]);
    }
  }
  #pragma unroll
  for (int mt=0;mt<4;++mt)
    #pragma unroll
    for (int nt=0;nt<4;++nt)
      #pragma unroll
      for (int r=0;r<4;++r){
        int mloc = mt*16+quad*4+r;
        int col  = wv*64+nt*16+nl;
        float v = acc[mt][nt][r]; v = v>0.f? v:0.f;
        uint32_t fidx = (uint32_t)(r0+mloc)*256u + (uint32_t)col;
        v = (part_unif(k2a,k2b,fidx) < 0.5f) ? v*2.0f : 0.0f;
        preo[(size_t)(r0+mloc)*256+col]=f2bf(v);
      }
}

// ---------------- processed_memory (bf16 out) ----------------
__global__ __launch_bounds__(256) void k_pm(
  const float* __restrict__ memory, const float* __restrict__ mw, ushortT* __restrict__ pmB)
{
  int row = blockIdx.x*2 + (threadIdx.x>>7);
  int col = threadIdx.x & 127;
  const float* mr = memory + (size_t)row*512;
  const float* wr = mw + (size_t)col*512;
  float acc=0.f;
  for (int k=0;k<512;k+=4){
    float4 a=*(const float4*)(mr+k), b=*(const float4*)(wr+k);
    acc += a.x*b.x + a.y*b.y + a.z*b.z + a.w*b.w;
  }
  pmB[(size_t)row*128+col]=f2bf(acc);
}

// ---------------- phase: attention LSTM (64 WGs) + pq partials ----------------
__device__ __forceinline__ void phaseA(SmemU* sm, int t, int ablk, int tid,
  const ushortT* Wai, const ushortT* Wah, const float* abih, const float* abhh,
  const ushortT* preo, const ushortT* AHp, ushortT* AHn, const ushortT* CTX,
  float* ac, float* pq, const ushortT* qwB, uint32_t k3a, uint32_t k3b)
{
  SmemL* L = &sm->l;
  int lane=tid&63, wv=tid>>6, quad=lane>>4, nl=lane&15;
  int u0 = ablk*16;
  int rown = wv*1024 + u0 + nl;
  const ushortT* bh = Wah + (size_t)rown*1024 + quad*8;
  const ushortT* bx = Wai + (size_t)rown*768  + quad*8;
  const ushortT* a0 = AHp + (size_t)nl*1024 + quad*8;  const ushortT* a1 = a0 + 16*1024;
  const ushortT* c0p= CTX + (size_t)nl*512  + quad*8;  const ushortT* c1p= c0p + 16*512;
  const ushortT* p0 = preo + ((size_t)t*32 + nl)*256 + quad*8; const ushortT* p1 = p0 + 16*256;
  f4v acc0={0,0,0,0}, acc1={0,0,0,0};
  for (int kb=0;kb<32;++kb){ s8v bb=*(const s8v*)(bh+kb*32);
    acc0=mfma16(*(const s8v*)(a0+kb*32),bb,acc0); acc1=mfma16(*(const s8v*)(a1+kb*32),bb,acc1); }
  for (int kb=0;kb<8;++kb){ s8v bb=*(const s8v*)(bx+kb*32);
    acc0=mfma16(*(const s8v*)(p0+kb*32),bb,acc0); acc1=mfma16(*(const s8v*)(p1+kb*32),bb,acc1); }
  for (int kb=0;kb<16;++kb){ s8v bb=*(const s8v*)(bx+256+kb*32);
    acc0=mfma16(*(const s8v*)(c0p+kb*32),bb,acc0); acc1=mfma16(*(const s8v*)(c1p+kb*32),bb,acc1); }
  #pragma unroll
  for (int r=0;r<4;++r){ L->gbuf[wv][quad*4+r][nl]=acc0[r]; L->gbuf[wv][quad*4+r+16][nl]=acc1[r]; }
  __syncthreads();
  for (int idx=tid; idx<512; idx+=256){
    int b=idx&31, ul=idx>>5; int u=u0+ul;
    float gi=L->gbuf[0][b][ul]+abih[u]       +abhh[u];
    float gf=L->gbuf[1][b][ul]+abih[1024+u]  +abhh[1024+u];
    float gg=L->gbuf[2][b][ul]+abih[2048+u]  +abhh[2048+u];
    float go=L->gbuf[3][b][ul]+abih[3072+u]  +abhh[3072+u];
    float cp=ac[b*1024+u];
    float c2=sigm(gf)*cp + sigm(gi)*tanhf(gg);
    float h =sigm(go)*tanhf(c2);
    uint32_t fidx=((uint32_t)(t*32+b))*1024u+(uint32_t)u;
    h = (part_unif(k3a,k3b,fidx) < 0.9f) ? h*(1.0f/0.9f) : 0.0f;
    ac[b*1024+u]=c2;
    AHn[b*1024+u]=f2bf(h);
    L->ahs[b*17+ul]=h;
  }
  __syncthreads();
  // stage qw slice: qsl[a][u] for a in [0,128), u in slice
  for (int i=tid;i<2048;i+=256){ int a=i>>4,u=i&15; L->qsl[a*17+u]=bf2f(qwB[(size_t)a*1024+u0+u]); }
  __syncthreads();
  // pq partial: pq[b][a] += sum_u ah[b][u]*qw[a][u]
  int b=tid&31, ag=tid>>5;
  for (int j=0;j<16;++j){
    int a=ag*16+j;
    float s=0.f;
    #pragma unroll
    for (int u=0;u<16;++u) s += L->ahs[b*17+u]*L->qsl[a*17+u];
    atomicAdd(&pq[b*128+a], s);
  }
}

// ---------------- phase: decoder LSTM (64 WGs) ----------------
__device__ __forceinline__ void phaseC(SmemU* sm, int t, int cblk, int tid,
  const ushortT* Wdi, const ushortT* Wdh, const float* dbih, const float* dbhh,
  const ushortT* AHc, const ushortT* CTX, const ushortT* DHp, ushortT* DHn,
  float* dc, uint32_t k4a, uint32_t k4b)
{
  SmemL* L = &sm->l;
  int lane=tid&63, wv=tid>>6, quad=lane>>4, nl=lane&15;
  int u0 = cblk*16;
  int rown = wv*1024 + u0 + nl;
  const ushortT* bh = Wdh + (size_t)rown*1024 + quad*8;
  const ushortT* bx = Wdi + (size_t)rown*1536 + quad*8;
  const ushortT* a0 = AHc + (size_t)nl*1024 + quad*8;  const ushortT* a1 = a0 + 16*1024;
  const ushortT* c0p= CTX + (size_t)nl*512  + quad*8;  const ushortT* c1p= c0p + 16*512;
  const ushortT* d0 = DHp + (size_t)nl*1024 + quad*8;  const ushortT* d1 = d0 + 16*1024;
  f4v acc0={0,0,0,0}, acc1={0,0,0,0};
  for (int kb=0;kb<32;++kb){ s8v bb=*(const s8v*)(bx+kb*32);
    acc0=mfma16(*(const s8v*)(a0+kb*32),bb,acc0); acc1=mfma16(*(const s8v*)(a1+kb*32),bb,acc1); }
  for (int kb=0;kb<16;++kb){ s8v bb=*(const s8v*)(bx+1024+kb*32);
    acc0=mfma16(*(const s8v*)(c0p+kb*32),bb,acc0); acc1=mfma16(*(const s8v*)(c1p+kb*32),bb,acc1); }
  for (int kb=0;kb<32;++kb){ s8v bb=*(const s8v*)(bh+kb*32);
    acc0=mfma16(*(const s8v*)(d0+kb*32),bb,acc0); acc1=mfma16(*(const s8v*)(d1+kb*32),bb,acc1); }
  #pragma unroll
  for (int r=0;r<4;++r){ L->gbuf[wv][quad*4+r][nl]=acc0[r]; L->gbuf[wv][quad*4+r+16][nl]=acc1[r]; }
  __syncthreads();
  for (int idx=tid; idx<512; idx+=256){
    int b=idx&31, ul=idx>>5; int u=u0+ul;
    float gi=L->gbuf[0][b][ul]+dbih[u]      +dbhh[u];
    float gf=L->gbuf[1][b][ul]+dbih[1024+u] +dbhh[1024+u];
    float gg=L->gbuf[2][b][ul]+dbih[2048+u] +dbhh[2048+u];
    float go=L->gbuf[3][b][ul]+dbih[3072+u] +dbhh[3072+u];
    float cp=dc[b*1024+u];
    float c2=sigm(gf)*cp + sigm(gi)*tanhf(gg);
    float h =sigm(go)*tanhf(c2);
    uint32_t fidx=((uint32_t)(t*32+b))*1024u+(uint32_t)u;
    h = (part_unif(k4a,k4b,fidx) < 0.9f) ? h*(1.0f/0.9f) : 0.0f;
    dc[b*1024+u]=c2;
    DHn[b*1024+u]=f2bf(h);
  }
}

// ---------------- phase: projection of step td (6 WGs) ----------------
__device__ __forceinline__ void phaseProj(SmemU* sm, int td, int wgd, int tid,
  const ushortT* Wpg, const float* pjb, const float* gb,
  const ushortT* DHd, const ushortT* CTX, float* out_mel, float* out_gate)
{
  SmemPj* P = &sm->pj;
  int lane=tid&63, wv=tid>>6, quad=lane>>4, nl=lane&15;
  int rb = wgd*16;
  int mt = wv&1, kh = wv>>1;
  int mrow = nl + mt*16;
  const ushortT* br  = Wpg + (size_t)(rb+nl)*1536 + quad*8;
  const ushortT* dhp = DHd + (size_t)mrow*1024 + quad*8;
  const ushortT* cxp = CTX + (size_t)mrow*512  + quad*8;
  f4v acc={0,0,0,0};
  for (int kb=0;kb<24;++kb){
    int kk = kh*768 + kb*32;
    s8v aa = (kk < 1024) ? *(const s8v*)(dhp + kk) : *(const s8v*)(cxp + (kk-1024));
    s8v bb = *(const s8v*)(br + kk);
    acc = mfma16(aa,bb,acc);
  }
  #pragma unroll
  for (int r=0;r<4;++r) P->dsum[kh][mt*16+quad*4+r][nl]=acc[r];
  __syncthreads();
  for (int idx=tid; idx<512; idx+=256){
    int m=idx>>4, n=idx&15;
    float v = P->dsum[0][m][n] + P->dsum[1][m][n];
    int r = rb + n;
    if (r < 80){
      v += pjb[r];
      out_mel[(size_t)(m*80+r)*500 + td] = v;
    } else if (r == 80){
      v += gb[0];
      out_gate[(size_t)m*500 + td] = v;
    }
  }
}

// ---------------- phase: location conv + energies (128 WGs) ----------------
__device__ __forceinline__ void phaseB1(SmemU* sm, int t, int blk, int tid,
  const float* lcw, const float* llw, const float* vw,
  const float* aw, const float* awc, const ushortT* pmB, const float* pq,
  const int* mlen, float* ebuf)
{
  SmemB1* S = &sm->b1;
  int b=blk>>2, ch=blk&3; int t0=ch*100;
  for (int i=tid;i<130;i+=256){
    int tt=t0-15+i; float a=0.f,c=0.f;
    if (tt>=0 && tt<TIN){ a=aw[b*TIN+tt]; c=awc[b*TIN+tt]; }
    S->awp[i]=a; S->awcp[i]=c;
  }
  for (int i=tid;i<992;i+=256){
    int f=i/31, j=i-f*31;
    S->cw0[i]=lcw[(f*2+0)*31+j];
    S->cw1[i]=lcw[(f*2+1)*31+j];
  }
  for (int i=tid;i<4096;i+=256){ int a=i>>5,f=i&31; S->lw[a*33+f]=llw[i]; }
  if (tid<128){ S->vv[tid]=vw[tid]; S->pqv[tid]=pq[b*128+tid]; }
  __syncthreads();
  for (int it=tid; it<3200; it+=256){
    int tl=it>>5, f=it&31;
    const float* c0=S->cw0+f*31; const float* c1=S->cw1+f*31;
    float s=0.f;
    #pragma unroll
    for (int j=0;j<31;++j) s += S->awp[tl+j]*c0[j] + S->awcp[tl+j]*c1[j];
    S->locl[tl*32+f]=s;
  }
  __syncthreads();
  {
    int a=tid&127, g=tid>>7, wid=tid>>6;
    const float* lwa = S->lw + a*33;
    for (int tl=g; tl<100; tl+=2){
      const float* lt = S->locl + tl*32;
      float l2=0.f;
      #pragma unroll
      for (int f=0;f<32;++f) l2 += lt[f]*lwa[f];
      float x = S->pqv[a] + l2 + bf2f(pmB[((size_t)b*TIN + (t0+tl))*128 + a]);
      float cv = S->vv[a]*tanhf(x);
      #pragma unroll
      for (int o=32;o>0;o>>=1) cv += __shfl_xor(cv,o);
      if ((tid&63)==0) S->epart[tl*2+(wid&1)]=cv;
    }
  }
  __syncthreads();
  if (tid<100){
    int tg=t0+tid;
    float e = S->epart[tid*2]+S->epart[tid*2+1];
    if (tg >= mlen[b]) e = -__builtin_inff();
    ebuf[b*TIN+tg]=e;
  }
}

// ---------------- phase: softmax + context quarter (128 WGs) ----------------
__device__ __forceinline__ void phaseB2(SmemU* sm, int t, int blk, int tid,
  const float* ebuf, const ushortT* memB,
  float* aw, float* awc, ushortT* CTX, float* out_align)
{
  SmemB2* S = &sm->b2;
  int b=blk>>2, q=blk&3, wid=tid>>6;
  float lm = -__builtin_inff();
  for (int i=tid;i<400;i+=256){ float v=ebuf[b*TIN+i]; S->p[i]=v; lm=fmaxf(lm,v); }
  #pragma unroll
  for (int o=32;o>0;o>>=1) lm=fmaxf(lm,__shfl_xor(lm,o));
  if ((tid&63)==0) S->red[wid]=lm;
  __syncthreads();
  float mx = fmaxf(fmaxf(S->red[0],S->red[1]),fmaxf(S->red[2],S->red[3]));
  if (!(mx > -__builtin_inff())) mx = 0.f;
  float ls=0.f;
  for (int i=tid;i<400;i+=256){ float pe=__expf(S->p[i]-mx); S->p[i]=pe; ls+=pe; }
  #pragma unroll
  for (int o=32;o>0;o>>=1) ls += __shfl_xor(ls,o);
  if ((tid&63)==0) S->red[4+wid]=ls;
  __syncthreads();
  float Ssum = S->red[4]+S->red[5]+S->red[6]+S->red[7];
  float rS = (Ssum>0.f) ? 1.0f/Ssum : 0.f;
  for (int i=tid;i<400;i+=256){
    float a2 = S->p[i]*rS; S->p[i]=a2;
    if (q==0){
      aw[b*TIN+i]=a2;
      awc[b*TIN+i]+=a2;
      out_align[((size_t)b*500 + t)*400 + i]=a2;
    }
  }
  __syncthreads();
  int dl = tid&127, th = tid>>7;
  int d = q*128 + dl;
  const ushortT* mb = memB + (size_t)b*TIN*512 + d;
  float c=0.f;
  for (int tt=th*200; tt<th*200+200; ++tt) c += S->p[tt]*bf2f(mb[(size_t)tt*512]);
  S->part[tid]=c;
  __syncthreads();
  if (tid<128) CTX[b*512 + q*128 + tid] = f2bf(S->part[tid]+S->part[tid+128]);
}

// ---------------- the persistent loop kernel ----------------
__global__ __launch_bounds__(256,1) void k_loop(
  const ushortT* __restrict__ Wai, const ushortT* __restrict__ Wah,
  const float* __restrict__ abih, const float* __restrict__ abhh,
  const ushortT* __restrict__ Wdi, const ushortT* __restrict__ Wdh,
  const float* __restrict__ dbih, const float* __restrict__ dbhh,
  const ushortT* __restrict__ Wpg, const float* __restrict__ pjb, const float* __restrict__ gb,
  const ushortT* __restrict__ preo, const ushortT* __restrict__ qwB,
  const ushortT* __restrict__ pmB, const ushortT* __restrict__ memB,
  const float* __restrict__ lcw, const float* __restrict__ llw, const float* __restrict__ vw,
  const int* __restrict__ mlen,
  ushortT* __restrict__ AH0, ushortT* __restrict__ AH1,
  ushortT* __restrict__ DH0, ushortT* __restrict__ DH1,
  ushortT* __restrict__ CTX,
  float* __restrict__ ac, float* __restrict__ dc,
  float* __restrict__ aw, float* __restrict__ awc,
  float* __restrict__ ebuf, float* __restrict__ pq,
  float* __restrict__ out_mel, float* __restrict__ out_gate, float* __restrict__ out_align,
  int* __restrict__ bar,
  uint32_t k3a, uint32_t k3b, uint32_t k4a, uint32_t k4b)
{
  __shared__ SmemU sm;
  int blk=blockIdx.x, tid=threadIdx.x;
  int nb=0;
  // A(0): reads AH1 (zeros), CTX (zeros); writes AH0, pq partials
  if (blk>=128 && blk<192)
    phaseA(&sm, 0, blk-128, tid, Wai, Wah, abih, abhh, preo, AH1, AH0, CTX, ac, pq, qwB, k3a, k3b);
  gridbar(bar, (++nb)*256);
  for (int t=0; t<TOUT; ++t){
    const ushortT* AHc = (t&1)? AH1 : AH0;       // ah(t)
    ushortT* AHn = (t&1)? AH0 : AH1;             // ah(t+1) dest
    const ushortT* DHp = (t&1)? DH0 : DH1;       // dh(t-1)
    ushortT* DHn = (t&1)? DH1 : DH0;             // dh(t) dest
    // ---- phase 1: B1(t) on 0..127; proj(t-1) on 128..133 ----
    if (blk<128)
      phaseB1(&sm, t, blk, tid, lcw, llw, vw, aw, awc, pmB, pq, mlen, ebuf);
    else if (blk<134 && t>0)
      phaseProj(&sm, t-1, blk-128, tid, Wpg, pjb, gb, DHp, CTX, out_mel, out_gate);
    gridbar(bar, (++nb)*256);
    // ---- phase 2: B2(t) on 0..127; pq-zero on 128 ----
    if (blk<128)
      phaseB2(&sm, t, blk, tid, ebuf, memB, aw, awc, CTX, out_align);
    else if (blk==128){
      for (int i=tid;i<4096;i+=256) pq[i]=0.f;
    }
    gridbar(bar, (++nb)*256);
    // ---- phase 3: C(t) on 0..63; A(t+1) on 128..191 ----
    if (blk<64)
      phaseC(&sm, t, blk, tid, Wdi, Wdh, dbih, dbhh, AHc, CTX, DHp, DHn, dc, k4a, k4b);
    else if (blk>=128 && blk<192 && t+1<TOUT)
      phaseA(&sm, t+1, blk-128, tid, Wai, Wah, abih, abhh, preo, AHc, AHn, CTX, ac, pq, qwB, k3a, k3b);
    gridbar(bar, (++nb)*256);
  }
  // final projection of step 499 (dh(499)=DH1, ctx(499)=CTX)
  if (blk>=128 && blk<134)
    phaseProj(&sm, TOUT-1, blk-128, tid, Wpg, pjb, gb, DH1, CTX, out_mel, out_gate);
}

// ---------------- host ----------------
extern "C" void kernel_launch(void* const* d_in, const int* in_sizes, int n_in,
                              void* d_out, int out_size, void* d_ws, size_t ws_size,
                              hipStream_t stream) {
  (void)in_sizes; (void)n_in; (void)out_size; (void)ws_size;
  const float* memory  = (const float*)d_in[0];
  const float* dec_inp = (const float*)d_in[1];
  const int*   mlen    = (const int*)d_in[2];
  const float* pw1     = (const float*)d_in[3];
  const float* pw2     = (const float*)d_in[4];
  const float* awih    = (const float*)d_in[5];
  const float* awhh    = (const float*)d_in[6];
  const float* abih    = (const float*)d_in[7];
  const float* abhh    = (const float*)d_in[8];
  const float* qw      = (const float*)d_in[9];
  const float* mw      = (const float*)d_in[10];
  const float* vw      = (const float*)d_in[11];
  const float* lcw     = (const float*)d_in[12];
  const float* llw     = (const float*)d_in[13];
  const float* dwih    = (const float*)d_in[14];
  const float* dwhh    = (const float*)d_in[15];
  const float* dbih    = (const float*)d_in[16];
  const float* dbhh    = (const float*)d_in[17];
  const float* pjw     = (const float*)d_in[18];
  const float* pjb     = (const float*)d_in[19];
  const float* gw      = (const float*)d_in[20];
  const float* gb      = (const float*)d_in[21];

  char* w = (char*)d_ws;
  size_t off=0;
  auto alloc = [&](size_t n)->char*{ char* p=w+off; off=(off+n+255)&~(size_t)255; return p; };
  ushortT* Wai = (ushortT*)alloc(4096UL*768*2);
  ushortT* Wah = (ushortT*)alloc(4096UL*1024*2);
  ushortT* Wdi = (ushortT*)alloc(4096UL*1536*2);
  ushortT* Wdh = (ushortT*)alloc(4096UL*1024*2);
  ushortT* Wpg = (ushortT*)alloc(96UL*1536*2);
  ushortT* preo= (ushortT*)alloc(16000UL*256*2);
  ushortT* pmB = (ushortT*)alloc(12800UL*128*2);
  ushortT* memB= (ushortT*)alloc(32UL*400*512*2);
  ushortT* qwB = (ushortT*)alloc(128UL*1024*2);
  ushortT* AH0 = (ushortT*)alloc(32UL*1024*2);
  ushortT* AH1 = (ushortT*)alloc(32UL*1024*2);
  ushortT* DH0 = (ushortT*)alloc(32UL*1024*2);
  ushortT* DH1 = (ushortT*)alloc(32UL*1024*2);
  ushortT* CTX = (ushortT*)alloc(32UL*512*2);
  float*   ac  = (float*)alloc(32UL*1024*4);
  float*   dc  = (float*)alloc(32UL*1024*4);
  float*   aw  = (float*)alloc(12800UL*4);
  float*   awc = (float*)alloc(12800UL*4);
  float*   ebuf= (float*)alloc(12800UL*4);
  float*   pq  = (float*)alloc(4096UL*4);
  int*     bar = (int*)alloc(256);

  // JAX partitionable split(key(42), 4): subkey_i = threefry((0,42), (0, i))
  uint32_t K[4][2];
  for (uint32_t i=0;i<4;++i) tf2x32(0u,42u,0u,i,&K[i][0],&K[i][1]);

  float* out_mel   = (float*)d_out;
  float* out_gate  = out_mel + 1280000;
  float* out_align = out_mel + 1296000;

  k_setup<<<1024,256,0,stream>>>(awih,awhh,dwih,dwhh,pjw,gw,memory,qw,
                                 Wai,Wah,Wdi,Wdh,Wpg,memB,qwB,
                                 AH0,AH1,DH0,DH1,CTX,ac,dc,aw,awc,pq,bar);
  k_prenet<<<250,256,0,stream>>>(dec_inp, pw1, pw2, preo, K[0][0],K[0][1], K[1][0],K[1][1]);
  k_pm<<<6400,256,0,stream>>>(memory, mw, pmB);
  k_loop<<<256,256,0,stream>>>(Wai,Wah,abih,abhh,Wdi,Wdh,dbih,dbhh,Wpg,pjb,gb,
                               preo,qwB,pmB,memB,lcw,llw,vw,mlen,
                               AH0,AH1,DH0,DH1,CTX,ac,dc,aw,awc,ebuf,pq,
                               out_mel,out_gate,out_align,bar,
                               K[2][0],K[2][1],K[3][0],K[3][1]);
}

// Round 5
// 107832.007 us; speedup vs baseline: 2.1703x; 2.1703x over previous
//
#include <hip/hip_runtime.h>
#include <cstdint>

typedef unsigned short ushortT;
typedef __attribute__((ext_vector_type(8))) short s8v;   // 8 bf16 (4 VGPRs)
typedef __attribute__((ext_vector_type(4))) float f4v;   // MFMA acc

#define B_  32
#define TIN 400
#define TOUT 500
#define NBLK 192

// ---------------- threefry2x32 (JAX, 20 rounds) ----------------
__host__ __device__ __forceinline__ uint32_t rotl32(uint32_t v, int r){ return (v<<r)|(v>>(32-r)); }
__host__ __device__ inline void tf2x32(uint32_t k0, uint32_t k1, uint32_t x0, uint32_t x1,
                                       uint32_t* o0, uint32_t* o1){
  uint32_t ks2 = k0 ^ k1 ^ 0x1BD11BDAu;
  x0 += k0; x1 += k1;
  x0+=x1; x1=rotl32(x1,13); x1^=x0;  x0+=x1; x1=rotl32(x1,15); x1^=x0;
  x0+=x1; x1=rotl32(x1,26); x1^=x0;  x0+=x1; x1=rotl32(x1, 6); x1^=x0;
  x0+=k1; x1+=ks2+1u;
  x0+=x1; x1=rotl32(x1,17); x1^=x0;  x0+=x1; x1=rotl32(x1,29); x1^=x0;
  x0+=x1; x1=rotl32(x1,16); x1^=x0;  x0+=x1; x1=rotl32(x1,24); x1^=x0;
  x0+=ks2; x1+=k0+2u;
  x0+=x1; x1=rotl32(x1,13); x1^=x0;  x0+=x1; x1=rotl32(x1,15); x1^=x0;
  x0+=x1; x1=rotl32(x1,26); x1^=x0;  x0+=x1; x1=rotl32(x1, 6); x1^=x0;
  x0+=k0; x1+=k1+3u;
  x0+=x1; x1=rotl32(x1,17); x1^=x0;  x0+=x1; x1=rotl32(x1,29); x1^=x0;
  x0+=x1; x1=rotl32(x1,16); x1^=x0;  x0+=x1; x1=rotl32(x1,24); x1^=x0;
  x0+=k1; x1+=ks2+4u;
  x0+=x1; x1=rotl32(x1,13); x1^=x0;  x0+=x1; x1=rotl32(x1,15); x1^=x0;
  x0+=x1; x1=rotl32(x1,26); x1^=x0;  x0+=x1; x1=rotl32(x1, 6); x1^=x0;
  x0+=ks2; x1+=k0+5u;
  *o0 = x0; *o1 = x1;
}
// JAX partitionable random_bits (32-bit): counter = (0, i), fold = o0 ^ o1
__device__ __forceinline__ float part_unif(uint32_t ka, uint32_t kb, uint32_t idx){
  uint32_t o0,o1; tf2x32(ka,kb,0u,idx,&o0,&o1);
  uint32_t bits = o0 ^ o1;
  return __uint_as_float(0x3f800000u | (bits>>9)) - 1.0f;
}

// ---------------- helpers ----------------
__device__ __forceinline__ float bf2f(ushortT u){ return __uint_as_float(((uint32_t)u)<<16); }
__device__ __forceinline__ ushortT f2bf(float f){
  uint32_t x = __float_as_uint(f);
  return (ushortT)((x + 0x7fffu + ((x>>16)&1u)) >> 16);
}
__device__ __forceinline__ float sigm(float x){ return 1.0f/(1.0f+__expf(-x)); }
__device__ __forceinline__ f4v mfma16(s8v a, s8v b, f4v c){
  return __builtin_amdgcn_mfma_f32_16x16x32_bf16(a,b,c,0,0,0);
}
__device__ __forceinline__ s8v pack8(const float* p){
  s8v r;
  #pragma unroll
  for (int j=0;j<8;++j) r[j]=(short)f2bf(p[j]);
  return r;
}

// ---------------- LDS union ----------------
struct SmemB1{ float awp[130],awcp[130],cw0[992],cw1[992],vv[128],pqv[128],epart[200]; float lw[4224]; float locl[3200]; };
struct SmemL { float gbuf[4][32][17]; float qsl[128*17]; float ahs[32*17]; };
struct SmemB2{ float p[400]; float red[8]; float part[256]; };
struct SmemPj{ float dsum[2][32][16]; };
union SmemU{ SmemB1 b1; SmemL l; SmemB2 b2; SmemPj pj; };

// ---------------- grid barrier: one wbl2 on arrive, RELAXED spin (no cacheops), one inv on depart ----------------
__device__ __forceinline__ void gridbar(int* bar, int tgt){
  __syncthreads();                 // all waves drain their vm/lgkm counts
  if (threadIdx.x==0){
    // release RMW: buffer_wbl2 once, then atomic add at coherence point (sc1)
    __hip_atomic_fetch_add(bar, 1, __ATOMIC_RELEASE, __HIP_MEMORY_SCOPE_AGENT);
    // relaxed polls: sc1 load from IF$, NO buffer_inv per iteration
    while (__hip_atomic_load(bar, __ATOMIC_RELAXED, __HIP_MEMORY_SCOPE_AGENT) < tgt)
      __builtin_amdgcn_s_sleep(16);
    // single acquire: one buffer_inv so subsequent plain loads see fresh data
    __builtin_amdgcn_fence(__ATOMIC_ACQUIRE, "agent");
  }
  __syncthreads();
}

// ---------------- setup ----------------
__global__ __launch_bounds__(256) void k_setup(
  const float* __restrict__ awih, const float* __restrict__ awhh,
  const float* __restrict__ dwih, const float* __restrict__ dwhh,
  const float* __restrict__ pjw,  const float* __restrict__ gw,
  const float* __restrict__ memory, const float* __restrict__ qw,
  ushortT* __restrict__ Wai, ushortT* __restrict__ Wah,
  ushortT* __restrict__ Wdi, ushortT* __restrict__ Wdh,
  ushortT* __restrict__ Wpg, ushortT* __restrict__ memB, ushortT* __restrict__ qwB,
  ushortT* __restrict__ AH0, ushortT* __restrict__ AH1,
  ushortT* __restrict__ DH0, ushortT* __restrict__ DH1,
  ushortT* __restrict__ CTX,
  float* __restrict__ ac, float* __restrict__ dc,
  float* __restrict__ aw, float* __restrict__ awc,
  float* __restrict__ pq, int* __restrict__ bar)
{
  int stride = gridDim.x*blockDim.x;
  int g0 = blockIdx.x*blockDim.x + threadIdx.x;
  for (int i=g0; i<4096*768;  i+=stride) Wai[i]=f2bf(awih[i]);
  for (int i=g0; i<4096*1024; i+=stride) Wah[i]=f2bf(awhh[i]);
  for (int i=g0; i<4096*1536; i+=stride) Wdi[i]=f2bf(dwih[i]);
  for (int i=g0; i<4096*1024; i+=stride) Wdh[i]=f2bf(dwhh[i]);
  for (int i=g0; i<32*400*512; i+=stride) memB[i]=f2bf(memory[i]);
  for (int i=g0; i<128*1024; i+=stride) qwB[i]=f2bf(qw[i]);
  for (int i=g0; i<96*1536; i+=stride){
    int r=i/1536, k=i-r*1536;
    ushortT v=0;
    if (r<80) v=f2bf(pjw[r*1536+k]);
    else if (r==80) v=f2bf(gw[k]);
    Wpg[i]=v;
  }
  for (int i=g0; i<32*1024; i+=stride){ ac[i]=0.f; dc[i]=0.f; AH0[i]=0; AH1[i]=0; DH0[i]=0; DH1[i]=0; }
  for (int i=g0; i<32*512;  i+=stride){ CTX[i]=0; }
  for (int i=g0; i<32*400;  i+=stride){ aw[i]=0.f; awc[i]=0.f; }
  for (int i=g0; i<32*128;  i+=stride){ pq[i]=0.f; }
  if (g0 < 64) bar[g0]=0;
}

// ---------------- fused prenet (verified) ----------------
__global__ __launch_bounds__(256) void k_prenet(
  const float* __restrict__ dec_inp, const float* __restrict__ w1, const float* __restrict__ w2,
  ushortT* __restrict__ preo,
  uint32_t k1a, uint32_t k1b, uint32_t k2a, uint32_t k2b)
{
  __shared__ ushortT Xs[64*96];
  __shared__ ushortT H1s[64*256];
  int tid=threadIdx.x, lane=tid&63, wv=tid>>6, quad=lane>>4, nl=lane&15;
  int r0 = blockIdx.x*64;
  for (int i=tid; i<64*96; i+=256){
    int rr=i/96, k=i-rr*96; int row=r0+rr; int s=row>>5, b=row&31;
    float v=0.f;
    if (k<80 && s>0) v = dec_inp[((size_t)b*80+k)*500 + (s-1)];
    Xs[i]=f2bf(v);
  }
  __syncthreads();
  f4v acc[4][4];
  #pragma unroll
  for (int mt=0;mt<4;++mt)
    #pragma unroll
    for (int nt=0;nt<4;++nt) acc[mt][nt]=(f4v){0,0,0,0};
  for (int kb=0;kb<3;++kb){
    int c0 = kb*32 + quad*8;
    s8v a[4];
    #pragma unroll
    for (int mt=0;mt<4;++mt) a[mt]=*(const s8v*)(Xs + (mt*16+nl)*96 + c0);
    #pragma unroll
    for (int nt=0;nt<4;++nt){
      int rown = wv*64+nt*16+nl;
      s8v bb;
      if (c0 < 80) bb = pack8(w1 + (size_t)rown*80 + c0);
      else { s8v z={0,0,0,0,0,0,0,0}; bb=z; }
      #pragma unroll
      for (int mt=0;mt<4;++mt) acc[mt][nt]=mfma16(a[mt],bb,acc[mt][nt]);
    }
  }
  #pragma unroll
  for (int mt=0;mt<4;++mt)
    #pragma unroll
    for (int nt=0;nt<4;++nt)
      #pragma unroll
      for (int r=0;r<4;++r){
        int mloc = mt*16+quad*4+r;
        int col  = wv*64+nt*16+nl;
        float v = acc[mt][nt][r]; v = v>0.f? v:0.f;
        uint32_t fidx = (uint32_t)(r0+mloc)*256u + (uint32_t)col;
        v = (part_unif(k1a,k1b,fidx) < 0.5f) ? v*2.0f : 0.0f;
        H1s[mloc*256+col]=f2bf(v);
      }
  __syncthreads();
  #pragma unroll
  for (int mt=0;mt<4;++mt)
    #pragma unroll
    for (int nt=0;nt<4;++nt) acc[mt][nt]=(f4v){0,0,0,0};
  for (int kb=0;kb<8;++kb){
    int c0 = kb*32 + quad*8;
    s8v a[4];
    #pragma unroll
    for (int mt=0;mt<4;++mt) a[mt]=*(const s8v*)(H1s + (mt*16+nl)*256 + c0);
    #pragma unroll
    for (int nt=0;nt<4;++nt){
      int rown = wv*64+nt*16+nl;
      s8v bb = pack8(w2 + (size_t)rown*256 + c0);
      #pragma unroll
      for (int mt=0;mt<4;++mt) acc[mt][nt]=mfma16(a[mt],bb,acc[mt][nt]);
    }
  }
  #pragma unroll
  for (int mt=0;mt<4;++mt)
    #pragma unroll
    for (int nt=0;nt<4;++nt)
      #pragma unroll
      for (int r=0;r<4;++r){
        int mloc = mt*16+quad*4+r;
        int col  = wv*64+nt*16+nl;
        float v = acc[mt][nt][r]; v = v>0.f? v:0.f;
        uint32_t fidx = (uint32_t)(r0+mloc)*256u + (uint32_t)col;
        v = (part_unif(k2a,k2b,fidx) < 0.5f) ? v*2.0f : 0.0f;
        preo[(size_t)(r0+mloc)*256+col]=f2bf(v);
      }
}

// ---------------- processed_memory (bf16 out) ----------------
__global__ __launch_bounds__(256) void k_pm(
  const float* __restrict__ memory, const float* __restrict__ mw, ushortT* __restrict__ pmB)
{
  int row = blockIdx.x*2 + (threadIdx.x>>7);
  int col = threadIdx.x & 127;
  const float* mr = memory + (size_t)row*512;
  const float* wr = mw + (size_t)col*512;
  float acc=0.f;
  for (int k=0;k<512;k+=4){
    float4 a=*(const float4*)(mr+k), b=*(const float4*)(wr+k);
    acc += a.x*b.x + a.y*b.y + a.z*b.z + a.w*b.w;
  }
  pmB[(size_t)row*128+col]=f2bf(acc);
}

// ---------------- phase: attention LSTM (64 WGs) + pq partials ----------------
__device__ __forceinline__ void phaseA(SmemU* sm, int t, int ablk, int tid,
  const ushortT* Wai, const ushortT* Wah, const float* abih, const float* abhh,
  const ushortT* preo, const ushortT* AHp, ushortT* AHn, const ushortT* CTX,
  float* ac, float* pq, const ushortT* qwB, uint32_t k3a, uint32_t k3b)
{
  SmemL* L = &sm->l;
  int lane=tid&63, wv=tid>>6, quad=lane>>4, nl=lane&15;
  int u0 = ablk*16;
  int rown = wv*1024 + u0 + nl;
  const ushortT* bh = Wah + (size_t)rown*1024 + quad*8;
  const ushortT* bx = Wai + (size_t)rown*768  + quad*8;
  const ushortT* a0 = AHp + (size_t)nl*1024 + quad*8;  const ushortT* a1 = a0 + 16*1024;
  const ushortT* c0p= CTX + (size_t)nl*512  + quad*8;  const ushortT* c1p= c0p + 16*512;
  const ushortT* p0 = preo + ((size_t)t*32 + nl)*256 + quad*8; const ushortT* p1 = p0 + 16*256;
  f4v acc0={0,0,0,0}, acc1={0,0,0,0};
  for (int kb=0;kb<32;++kb){ s8v bb=*(const s8v*)(bh+kb*32);
    acc0=mfma16(*(const s8v*)(a0+kb*32),bb,acc0); acc1=mfma16(*(const s8v*)(a1+kb*32),bb,acc1); }
  for (int kb=0;kb<8;++kb){ s8v bb=*(const s8v*)(bx+kb*32);
    acc0=mfma16(*(const s8v*)(p0+kb*32),bb,acc0); acc1=mfma16(*(const s8v*)(p1+kb*32),bb,acc1); }
  for (int kb=0;kb<16;++kb){ s8v bb=*(const s8v*)(bx+256+kb*32);
    acc0=mfma16(*(const s8v*)(c0p+kb*32),bb,acc0); acc1=mfma16(*(const s8v*)(c1p+kb*32),bb,acc1); }
  #pragma unroll
  for (int r=0;r<4;++r){ L->gbuf[wv][quad*4+r][nl]=acc0[r]; L->gbuf[wv][quad*4+r+16][nl]=acc1[r]; }
  __syncthreads();
  for (int idx=tid; idx<512; idx+=256){
    int b=idx&31, ul=idx>>5; int u=u0+ul;
    float gi=L->gbuf[0][b][ul]+abih[u]       +abhh[u];
    float gf=L->gbuf[1][b][ul]+abih[1024+u]  +abhh[1024+u];
    float gg=L->gbuf[2][b][ul]+abih[2048+u]  +abhh[2048+u];
    float go=L->gbuf[3][b][ul]+abih[3072+u]  +abhh[3072+u];
    float cp=ac[b*1024+u];
    float c2=sigm(gf)*cp + sigm(gi)*tanhf(gg);
    float h =sigm(go)*tanhf(c2);
    uint32_t fidx=((uint32_t)(t*32+b))*1024u+(uint32_t)u;
    h = (part_unif(k3a,k3b,fidx) < 0.9f) ? h*(1.0f/0.9f) : 0.0f;
    ac[b*1024+u]=c2;
    AHn[b*1024+u]=f2bf(h);
    L->ahs[b*17+ul]=h;
  }
  __syncthreads();
  for (int i=tid;i<2048;i+=256){ int a=i>>4,u=i&15; L->qsl[a*17+u]=bf2f(qwB[(size_t)a*1024+u0+u]); }
  __syncthreads();
  int b=tid&31, ag=tid>>5;
  for (int j=0;j<16;++j){
    int a=ag*16+j;
    float s=0.f;
    #pragma unroll
    for (int u=0;u<16;++u) s += L->ahs[b*17+u]*L->qsl[a*17+u];
    atomicAdd(&pq[b*128+a], s);
  }
}

// ---------------- phase: decoder LSTM (64 WGs) ----------------
__device__ __forceinline__ void phaseC(SmemU* sm, int t, int cblk, int tid,
  const ushortT* Wdi, const ushortT* Wdh, const float* dbih, const float* dbhh,
  const ushortT* AHc, const ushortT* CTX, const ushortT* DHp, ushortT* DHn,
  float* dc, uint32_t k4a, uint32_t k4b)
{
  SmemL* L = &sm->l;
  int lane=tid&63, wv=tid>>6, quad=lane>>4, nl=lane&15;
  int u0 = cblk*16;
  int rown = wv*1024 + u0 + nl;
  const ushortT* bh = Wdh + (size_t)rown*1024 + quad*8;
  const ushortT* bx = Wdi + (size_t)rown*1536 + quad*8;
  const ushortT* a0 = AHc + (size_t)nl*1024 + quad*8;  const ushortT* a1 = a0 + 16*1024;
  const ushortT* c0p= CTX + (size_t)nl*512  + quad*8;  const ushortT* c1p= c0p + 16*512;
  const ushortT* d0 = DHp + (size_t)nl*1024 + quad*8;  const ushortT* d1 = d0 + 16*1024;
  f4v acc0={0,0,0,0}, acc1={0,0,0,0};
  for (int kb=0;kb<32;++kb){ s8v bb=*(const s8v*)(bx+kb*32);
    acc0=mfma16(*(const s8v*)(a0+kb*32),bb,acc0); acc1=mfma16(*(const s8v*)(a1+kb*32),bb,acc1); }
  for (int kb=0;kb<16;++kb){ s8v bb=*(const s8v*)(bx+1024+kb*32);
    acc0=mfma16(*(const s8v*)(c0p+kb*32),bb,acc0); acc1=mfma16(*(const s8v*)(c1p+kb*32),bb,acc1); }
  for (int kb=0;kb<32;++kb){ s8v bb=*(const s8v*)(bh+kb*32);
    acc0=mfma16(*(const s8v*)(d0+kb*32),bb,acc0); acc1=mfma16(*(const s8v*)(d1+kb*32),bb,acc1); }
  #pragma unroll
  for (int r=0;r<4;++r){ L->gbuf[wv][quad*4+r][nl]=acc0[r]; L->gbuf[wv][quad*4+r+16][nl]=acc1[r]; }
  __syncthreads();
  for (int idx=tid; idx<512; idx+=256){
    int b=idx&31, ul=idx>>5; int u=u0+ul;
    float gi=L->gbuf[0][b][ul]+dbih[u]      +dbhh[u];
    float gf=L->gbuf[1][b][ul]+dbih[1024+u] +dbhh[1024+u];
    float gg=L->gbuf[2][b][ul]+dbih[2048+u] +dbhh[2048+u];
    float go=L->gbuf[3][b][ul]+dbih[3072+u] +dbhh[3072+u];
    float cp=dc[b*1024+u];
    float c2=sigm(gf)*cp + sigm(gi)*tanhf(gg);
    float h =sigm(go)*tanhf(c2);
    uint32_t fidx=((uint32_t)(t*32+b))*1024u+(uint32_t)u;
    h = (part_unif(k4a,k4b,fidx) < 0.9f) ? h*(1.0f/0.9f) : 0.0f;
    dc[b*1024+u]=c2;
    DHn[b*1024+u]=f2bf(h);
  }
}

// ---------------- phase: projection of step td (6 WGs) ----------------
__device__ __forceinline__ void phaseProj(SmemU* sm, int td, int wgd, int tid,
  const ushortT* Wpg, const float* pjb, const float* gb,
  const ushortT* DHd, const ushortT* CTX, float* out_mel, float* out_gate)
{
  SmemPj* P = &sm->pj;
  int lane=tid&63, wv=tid>>6, quad=lane>>4, nl=lane&15;
  int rb = wgd*16;
  int mt = wv&1, kh = wv>>1;
  int mrow = nl + mt*16;
  const ushortT* br  = Wpg + (size_t)(rb+nl)*1536 + quad*8;
  const ushortT* dhp = DHd + (size_t)mrow*1024 + quad*8;
  const ushortT* cxp = CTX + (size_t)mrow*512  + quad*8;
  f4v acc={0,0,0,0};
  for (int kb=0;kb<24;++kb){
    int kk = kh*768 + kb*32;
    s8v aa = (kk < 1024) ? *(const s8v*)(dhp + kk) : *(const s8v*)(cxp + (kk-1024));
    s8v bb = *(const s8v*)(br + kk);
    acc = mfma16(aa,bb,acc);
  }
  #pragma unroll
  for (int r=0;r<4;++r) P->dsum[kh][mt*16+quad*4+r][nl]=acc[r];
  __syncthreads();
  for (int idx=tid; idx<512; idx+=256){
    int m=idx>>4, n=idx&15;
    float v = P->dsum[0][m][n] + P->dsum[1][m][n];
    int r = rb + n;
    if (r < 80){
      v += pjb[r];
      out_mel[(size_t)(m*80+r)*500 + td] = v;
    } else if (r == 80){
      v += gb[0];
      out_gate[(size_t)m*500 + td] = v;
    }
  }
}

// ---------------- phase: location conv + energies (128 WGs) ----------------
__device__ __forceinline__ void phaseB1(SmemU* sm, int t, int blk, int tid,
  const float* lcw, const float* llw, const float* vw,
  const float* aw, const float* awc, const ushortT* pmB, const float* pq,
  const int* mlen, float* ebuf)
{
  SmemB1* S = &sm->b1;
  int b=blk>>2, ch=blk&3; int t0=ch*100;
  for (int i=tid;i<130;i+=256){
    int tt=t0-15+i; float a=0.f,c=0.f;
    if (tt>=0 && tt<TIN){ a=aw[b*TIN+tt]; c=awc[b*TIN+tt]; }
    S->awp[i]=a; S->awcp[i]=c;
  }
  for (int i=tid;i<992;i+=256){
    int f=i/31, j=i-f*31;
    S->cw0[i]=lcw[(f*2+0)*31+j];
    S->cw1[i]=lcw[(f*2+1)*31+j];
  }
  for (int i=tid;i<4096;i+=256){ int a=i>>5,f=i&31; S->lw[a*33+f]=llw[i]; }
  if (tid<128){ S->vv[tid]=vw[tid]; S->pqv[tid]=pq[b*128+tid]; }
  __syncthreads();
  for (int it=tid; it<3200; it+=256){
    int tl=it>>5, f=it&31;
    const float* c0=S->cw0+f*31; const float* c1=S->cw1+f*31;
    float s=0.f;
    #pragma unroll
    for (int j=0;j<31;++j) s += S->awp[tl+j]*c0[j] + S->awcp[tl+j]*c1[j];
    S->locl[tl*32+f]=s;
  }
  __syncthreads();
  {
    int a=tid&127, g=tid>>7, wid=tid>>6;
    const float* lwa = S->lw + a*33;
    for (int tl=g; tl<100; tl+=2){
      const float* lt = S->locl + tl*32;
      float l2=0.f;
      #pragma unroll
      for (int f=0;f<32;++f) l2 += lt[f]*lwa[f];
      float x = S->pqv[a] + l2 + bf2f(pmB[((size_t)b*TIN + (t0+tl))*128 + a]);
      float cv = S->vv[a]*tanhf(x);
      #pragma unroll
      for (int o=32;o>0;o>>=1) cv += __shfl_xor(cv,o);
      if ((tid&63)==0) S->epart[tl*2+(wid&1)]=cv;
    }
  }
  __syncthreads();
  if (tid<100){
    int tg=t0+tid;
    float e = S->epart[tid*2]+S->epart[tid*2+1];
    if (tg >= mlen[b]) e = -__builtin_inff();
    ebuf[b*TIN+tg]=e;
  }
}

// ---------------- phase: softmax + context quarter (128 WGs) ----------------
__device__ __forceinline__ void phaseB2(SmemU* sm, int t, int blk, int tid,
  const float* ebuf, const ushortT* memB,
  float* aw, float* awc, ushortT* CTX, float* out_align)
{
  SmemB2* S = &sm->b2;
  int b=blk>>2, q=blk&3, wid=tid>>6;
  float lm = -__builtin_inff();
  for (int i=tid;i<400;i+=256){ float v=ebuf[b*TIN+i]; S->p[i]=v; lm=fmaxf(lm,v); }
  #pragma unroll
  for (int o=32;o>0;o>>=1) lm=fmaxf(lm,__shfl_xor(lm,o));
  if ((tid&63)==0) S->red[wid]=lm;
  __syncthreads();
  float mx = fmaxf(fmaxf(S->red[0],S->red[1]),fmaxf(S->red[2],S->red[3]));
  if (!(mx > -__builtin_inff())) mx = 0.f;
  float ls=0.f;
  for (int i=tid;i<400;i+=256){ float pe=__expf(S->p[i]-mx); S->p[i]=pe; ls+=pe; }
  #pragma unroll
  for (int o=32;o>0;o>>=1) ls += __shfl_xor(ls,o);
  if ((tid&63)==0) S->red[4+wid]=ls;
  __syncthreads();
  float Ssum = S->red[4]+S->red[5]+S->red[6]+S->red[7];
  float rS = (Ssum>0.f) ? 1.0f/Ssum : 0.f;
  for (int i=tid;i<400;i+=256){
    float a2 = S->p[i]*rS; S->p[i]=a2;
    if (q==0){
      aw[b*TIN+i]=a2;
      awc[b*TIN+i]+=a2;
      out_align[((size_t)b*500 + t)*400 + i]=a2;
    }
  }
  __syncthreads();
  int dl = tid&127, th = tid>>7;
  int d = q*128 + dl;
  const ushortT* mb = memB + (size_t)b*TIN*512 + d;
  float c=0.f;
  for (int tt=th*200; tt<th*200+200; ++tt) c += S->p[tt]*bf2f(mb[(size_t)tt*512]);
  S->part[tid]=c;
  __syncthreads();
  if (tid<128) CTX[b*512 + q*128 + tid] = f2bf(S->part[tid]+S->part[tid+128]);
}

// ---------------- the persistent loop kernel ----------------
__global__ __launch_bounds__(256,1) void k_loop(
  const ushortT* __restrict__ Wai, const ushortT* __restrict__ Wah,
  const float* __restrict__ abih, const float* __restrict__ abhh,
  const ushortT* __restrict__ Wdi, const ushortT* __restrict__ Wdh,
  const float* __restrict__ dbih, const float* __restrict__ dbhh,
  const ushortT* __restrict__ Wpg, const float* __restrict__ pjb, const float* __restrict__ gb,
  const ushortT* __restrict__ preo, const ushortT* __restrict__ qwB,
  const ushortT* __restrict__ pmB, const ushortT* __restrict__ memB,
  const float* __restrict__ lcw, const float* __restrict__ llw, const float* __restrict__ vw,
  const int* __restrict__ mlen,
  ushortT* __restrict__ AH0, ushortT* __restrict__ AH1,
  ushortT* __restrict__ DH0, ushortT* __restrict__ DH1,
  ushortT* __restrict__ CTX,
  float* __restrict__ ac, float* __restrict__ dc,
  float* __restrict__ aw, float* __restrict__ awc,
  float* __restrict__ ebuf, float* __restrict__ pq,
  float* __restrict__ out_mel, float* __restrict__ out_gate, float* __restrict__ out_align,
  int* __restrict__ bar,
  uint32_t k3a, uint32_t k3b, uint32_t k4a, uint32_t k4b)
{
  __shared__ SmemU sm;
  int blk=blockIdx.x, tid=threadIdx.x;
  int nb=0;
  // A(0): reads AH1 (zeros), CTX (zeros); writes AH0, pq partials
  if (blk>=128 && blk<192)
    phaseA(&sm, 0, blk-128, tid, Wai, Wah, abih, abhh, preo, AH1, AH0, CTX, ac, pq, qwB, k3a, k3b);
  gridbar(bar, (++nb)*NBLK);
  for (int t=0; t<TOUT; ++t){
    const ushortT* AHc = (t&1)? AH1 : AH0;       // ah(t)
    ushortT* AHn = (t&1)? AH0 : AH1;             // ah(t+1) dest
    const ushortT* DHp = (t&1)? DH0 : DH1;       // dh(t-1)
    ushortT* DHn = (t&1)? DH1 : DH0;             // dh(t) dest
    // ---- phase 1: B1(t) on 0..127; proj(t-1) on 128..133 ----
    if (blk<128)
      phaseB1(&sm, t, blk, tid, lcw, llw, vw, aw, awc, pmB, pq, mlen, ebuf);
    else if (blk<134 && t>0)
      phaseProj(&sm, t-1, blk-128, tid, Wpg, pjb, gb, DHp, CTX, out_mel, out_gate);
    gridbar(bar, (++nb)*NBLK);
    // ---- phase 2: B2(t) on 0..127; pq-zero on 128 ----
    if (blk<128)
      phaseB2(&sm, t, blk, tid, ebuf, memB, aw, awc, CTX, out_align);
    else if (blk==128){
      for (int i=tid;i<4096;i+=256) pq[i]=0.f;
    }
    gridbar(bar, (++nb)*NBLK);
    // ---- phase 3: C(t) on 0..63; A(t+1) on 128..191 ----
    if (blk<64)
      phaseC(&sm, t, blk, tid, Wdi, Wdh, dbih, dbhh, AHc, CTX, DHp, DHn, dc, k4a, k4b);
    else if (blk>=128 && blk<192 && t+1<TOUT)
      phaseA(&sm, t+1, blk-128, tid, Wai, Wah, abih, abhh, preo, AHc, AHn, CTX, ac, pq, qwB, k3a, k3b);
    gridbar(bar, (++nb)*NBLK);
  }
  // final projection of step 499 (dh(499)=DH1, ctx(499)=CTX)
  if (blk>=128 && blk<134)
    phaseProj(&sm, TOUT-1, blk-128, tid, Wpg, pjb, gb, DH1, CTX, out_mel, out_gate);
}

// ---------------- host ----------------
extern "C" void kernel_launch(void* const* d_in, const int* in_sizes, int n_in,
                              void* d_out, int out_size, void* d_ws, size_t ws_size,
                              hipStream_t stream) {
  (void)in_sizes; (void)n_in; (void)out_size; (void)ws_size;
  const float* memory  = (const float*)d_in[0];
  const float* dec_inp = (const float*)d_in[1];
  const int*   mlen    = (const int*)d_in[2];
  const float* pw1     = (const float*)d_in[3];
  const float* pw2     = (const float*)d_in[4];
  const float* awih    = (const float*)d_in[5];
  const float* awhh    = (const float*)d_in[6];
  const float* abih    = (const float*)d_in[7];
  const float* abhh    = (const float*)d_in[8];
  const float* qw      = (const float*)d_in[9];
  const float* mw      = (const float*)d_in[10];
  const float* vw      = (const float*)d_in[11];
  const float* lcw     = (const float*)d_in[12];
  const float* llw     = (const float*)d_in[13];
  const float* dwih    = (const float*)d_in[14];
  const float* dwhh    = (const float*)d_in[15];
  const float* dbih    = (const float*)d_in[16];
  const float* dbhh    = (const float*)d_in[17];
  const float* pjw     = (const float*)d_in[18];
  const float* pjb     = (const float*)d_in[19];
  const float* gw      = (const float*)d_in[20];
  const float* gb      = (const float*)d_in[21];

  char* w = (char*)d_ws;
  size_t off=0;
  auto alloc = [&](size_t n)->char*{ char* p=w+off; off=(off+n+255)&~(size_t)255; return p; };
  ushortT* Wai = (ushortT*)alloc(4096UL*768*2);
  ushortT* Wah = (ushortT*)alloc(4096UL*1024*2);
  ushortT* Wdi = (ushortT*)alloc(4096UL*1536*2);
  ushortT* Wdh = (ushortT*)alloc(4096UL*1024*2);
  ushortT* Wpg = (ushortT*)alloc(96UL*1536*2);
  ushortT* preo= (ushortT*)alloc(16000UL*256*2);
  ushortT* pmB = (ushortT*)alloc(12800UL*128*2);
  ushortT* memB= (ushortT*)alloc(32UL*400*512*2);
  ushortT* qwB = (ushortT*)alloc(128UL*1024*2);
  ushortT* AH0 = (ushortT*)alloc(32UL*1024*2);
  ushortT* AH1 = (ushortT*)alloc(32UL*1024*2);
  ushortT* DH0 = (ushortT*)alloc(32UL*1024*2);
  ushortT* DH1 = (ushortT*)alloc(32UL*1024*2);
  ushortT* CTX = (ushortT*)alloc(32UL*512*2);
  float*   ac  = (float*)alloc(32UL*1024*4);
  float*   dc  = (float*)alloc(32UL*1024*4);
  float*   aw  = (float*)alloc(12800UL*4);
  float*   awc = (float*)alloc(12800UL*4);
  float*   ebuf= (float*)alloc(12800UL*4);
  float*   pq  = (float*)alloc(4096UL*4);
  int*     bar = (int*)alloc(256);

  // JAX partitionable split(key(42), 4): subkey_i = threefry((0,42), (0, i))
  uint32_t K[4][2];
  for (uint32_t i=0;i<4;++i) tf2x32(0u,42u,0u,i,&K[i][0],&K[i][1]);

  float* out_mel   = (float*)d_out;
  float* out_gate  = out_mel + 1280000;
  float* out_align = out_mel + 1296000;

  k_setup<<<1024,256,0,stream>>>(awih,awhh,dwih,dwhh,pjw,gw,memory,qw,
                                 Wai,Wah,Wdi,Wdh,Wpg,memB,qwB,
                                 AH0,AH1,DH0,DH1,CTX,ac,dc,aw,awc,pq,bar);
  k_prenet<<<250,256,0,stream>>>(dec_inp, pw1, pw2, preo, K[0][0],K[0][1], K[1][0],K[1][1]);
  k_pm<<<6400,256,0,stream>>>(memory, mw, pmB);
  k_loop<<<NBLK,256,0,stream>>>(Wai,Wah,abih,abhh,Wdi,Wdh,dbih,dbhh,Wpg,pjb,gb,
                               preo,qwB,pmB,memB,lcw,llw,vw,mlen,
                               AH0,AH1,DH0,DH1,CTX,ac,dc,aw,awc,ebuf,pq,
                               out_mel,out_gate,out_align,bar,
                               K[2][0],K[2][1],K[3][0],K[3][1]);
}

// Round 6
// 106421.765 us; speedup vs baseline: 2.1991x; 1.0133x over previous
//
#include <hip/hip_runtime.h>
#include <cstdint>

typedef unsigned short ushortT;
typedef __attribute__((ext_vector_type(8))) short s8v;   // 8 bf16 (4 VGPRs)
typedef __attribute__((ext_vector_type(4))) float f4v;   // MFMA acc

#define B_  32
#define TIN 400
#define TOUT 500
#define NBLK 192

// ---------------- threefry2x32 (JAX, 20 rounds) ----------------
__host__ __device__ __forceinline__ uint32_t rotl32(uint32_t v, int r){ return (v<<r)|(v>>(32-r)); }
__host__ __device__ inline void tf2x32(uint32_t k0, uint32_t k1, uint32_t x0, uint32_t x1,
                                       uint32_t* o0, uint32_t* o1){
  uint32_t ks2 = k0 ^ k1 ^ 0x1BD11BDAu;
  x0 += k0; x1 += k1;
  x0+=x1; x1=rotl32(x1,13); x1^=x0;  x0+=x1; x1=rotl32(x1,15); x1^=x0;
  x0+=x1; x1=rotl32(x1,26); x1^=x0;  x0+=x1; x1=rotl32(x1, 6); x1^=x0;
  x0+=k1; x1+=ks2+1u;
  x0+=x1; x1=rotl32(x1,17); x1^=x0;  x0+=x1; x1=rotl32(x1,29); x1^=x0;
  x0+=x1; x1=rotl32(x1,16); x1^=x0;  x0+=x1; x1=rotl32(x1,24); x1^=x0;
  x0+=ks2; x1+=k0+2u;
  x0+=x1; x1=rotl32(x1,13); x1^=x0;  x0+=x1; x1=rotl32(x1,15); x1^=x0;
  x0+=x1; x1=rotl32(x1,26); x1^=x0;  x0+=x1; x1=rotl32(x1, 6); x1^=x0;
  x0+=k0; x1+=k1+3u;
  x0+=x1; x1=rotl32(x1,17); x1^=x0;  x0+=x1; x1=rotl32(x1,29); x1^=x0;
  x0+=x1; x1=rotl32(x1,16); x1^=x0;  x0+=x1; x1=rotl32(x1,24); x1^=x0;
  x0+=k1; x1+=ks2+4u;
  x0+=x1; x1=rotl32(x1,13); x1^=x0;  x0+=x1; x1=rotl32(x1,15); x1^=x0;
  x0+=x1; x1=rotl32(x1,26); x1^=x0;  x0+=x1; x1=rotl32(x1, 6); x1^=x0;
  x0+=ks2; x1+=k0+5u;
  *o0 = x0; *o1 = x1;
}
// JAX partitionable random_bits (32-bit): counter = (0, i), fold = o0 ^ o1
__device__ __forceinline__ float part_unif(uint32_t ka, uint32_t kb, uint32_t idx){
  uint32_t o0,o1; tf2x32(ka,kb,0u,idx,&o0,&o1);
  uint32_t bits = o0 ^ o1;
  return __uint_as_float(0x3f800000u | (bits>>9)) - 1.0f;
}

// ---------------- helpers ----------------
__device__ __forceinline__ float bf2f(ushortT u){ return __uint_as_float(((uint32_t)u)<<16); }
__device__ __forceinline__ ushortT f2bf(float f){
  uint32_t x = __float_as_uint(f);
  return (ushortT)((x + 0x7fffu + ((x>>16)&1u)) >> 16);
}
__device__ __forceinline__ float sigm(float x){ return 1.0f/(1.0f+__expf(-x)); }
__device__ __forceinline__ f4v mfma16(s8v a, s8v b, f4v c){
  return __builtin_amdgcn_mfma_f32_16x16x32_bf16(a,b,c,0,0,0);
}
__device__ __forceinline__ s8v pack8(const float* p){
  s8v r;
  #pragma unroll
  for (int j=0;j<8;++j) r[j]=(short)f2bf(p[j]);
  return r;
}

// ---- device-scope coherent accessors (sc1: bypass per-XCD L2, no cache-wide fences needed) ----
__device__ __forceinline__ float ld_f32c(const float* p){
  return __hip_atomic_load(p, __ATOMIC_RELAXED, __HIP_MEMORY_SCOPE_AGENT);
}
__device__ __forceinline__ void st_f32c(float* p, float v){
  __hip_atomic_store(p, v, __ATOMIC_RELAXED, __HIP_MEMORY_SCOPE_AGENT);
}
__device__ __forceinline__ uint64_t ld_u64c(const uint64_t* p){
  return __hip_atomic_load(p, __ATOMIC_RELAXED, __HIP_MEMORY_SCOPE_AGENT);
}
__device__ __forceinline__ void st_u64c(uint64_t* p, uint64_t v){
  __hip_atomic_store(p, v, __ATOMIC_RELAXED, __HIP_MEMORY_SCOPE_AGENT);
}
__device__ __forceinline__ s8v ld16c(const ushortT* p){
  union{ uint64_t q[2]; s8v v; } u;
  u.q[0] = ld_u64c((const uint64_t*)p);
  u.q[1] = ld_u64c((const uint64_t*)p + 1);
  return u.v;
}

// ---------------- LDS structs (dynamic shared; union max ~140 KB, gfx950 has 160 KB/CU) ----------------
struct SmemB1{ float awp[130],awcp[130],cw0[992],cw1[992],vv[128],pqv[128],epart[200]; float lw[4224]; float locl[3200]; };
struct SmemA { float gbuf[4][32][17]; float qsl[128*17]; float ahs[32*17]; ushortT stA[32*1032]; ushortT stC[32*520]; };
struct SmemC { float gbuf[4][32][17]; float dhs[32*17]; ushortT stA[32*1032]; ushortT stD[32*1032]; };
struct SmemB2{ float p[400]; float red[8]; float part[256]; };
struct SmemPj{ float dsum[2][32][16]; };
union SmemU{ SmemB1 b1; SmemA a; SmemC c; SmemB2 b2; SmemPj pj; };

// ---------------- grid barrier: release add, RELAXED spin, NO acquire (state uses sc1) ----------------
__device__ __forceinline__ void gridbar(int* bar, int tgt){
  __syncthreads();                 // drains all waves' outstanding (sc1) memory ops
  if (threadIdx.x==0){
    __hip_atomic_fetch_add(bar, 1, __ATOMIC_RELEASE, __HIP_MEMORY_SCOPE_AGENT);
    while (__hip_atomic_load(bar, __ATOMIC_RELAXED, __HIP_MEMORY_SCOPE_AGENT) < tgt)
      __builtin_amdgcn_s_sleep(2);
  }
  __syncthreads();
}

// ---------------- setup ----------------
__global__ __launch_bounds__(256) void k_setup(
  const float* __restrict__ awih, const float* __restrict__ awhh,
  const float* __restrict__ dwih, const float* __restrict__ dwhh,
  const float* __restrict__ pjw,  const float* __restrict__ gw,
  const float* __restrict__ memory, const float* __restrict__ qw,
  ushortT* __restrict__ Wai, ushortT* __restrict__ Wah,
  ushortT* __restrict__ Wdi, ushortT* __restrict__ Wdh,
  ushortT* __restrict__ Wpg, ushortT* __restrict__ memB, ushortT* __restrict__ qwB,
  ushortT* __restrict__ AH0, ushortT* __restrict__ AH1,
  ushortT* __restrict__ DH0, ushortT* __restrict__ DH1,
  ushortT* __restrict__ CTX,
  float* __restrict__ ac, float* __restrict__ dc,
  float* __restrict__ aw, float* __restrict__ awc,
  float* __restrict__ pq, int* __restrict__ bar)
{
  int stride = gridDim.x*blockDim.x;
  int g0 = blockIdx.x*blockDim.x + threadIdx.x;
  for (int i=g0; i<4096*768;  i+=stride) Wai[i]=f2bf(awih[i]);
  for (int i=g0; i<4096*1024; i+=stride) Wah[i]=f2bf(awhh[i]);
  for (int i=g0; i<4096*1536; i+=stride) Wdi[i]=f2bf(dwih[i]);
  for (int i=g0; i<4096*1024; i+=stride) Wdh[i]=f2bf(dwhh[i]);
  for (int i=g0; i<32*400*512; i+=stride) memB[i]=f2bf(memory[i]);
  for (int i=g0; i<128*1024; i+=stride) qwB[i]=f2bf(qw[i]);
  for (int i=g0; i<96*1536; i+=stride){
    int r=i/1536, k=i-r*1536;
    ushortT v=0;
    if (r<80) v=f2bf(pjw[r*1536+k]);
    else if (r==80) v=f2bf(gw[k]);
    Wpg[i]=v;
  }
  for (int i=g0; i<32*1024; i+=stride){ ac[i]=0.f; dc[i]=0.f; AH0[i]=0; AH1[i]=0; DH0[i]=0; DH1[i]=0; }
  for (int i=g0; i<32*512;  i+=stride){ CTX[i]=0; }
  for (int i=g0; i<32*400;  i+=stride){ aw[i]=0.f; awc[i]=0.f; }
  for (int i=g0; i<32*128;  i+=stride){ pq[i]=0.f; }
  if (g0 < 64) bar[g0]=0;
}

// ---------------- fused prenet (verified) ----------------
__global__ __launch_bounds__(256) void k_prenet(
  const float* __restrict__ dec_inp, const float* __restrict__ w1, const float* __restrict__ w2,
  ushortT* __restrict__ preo,
  uint32_t k1a, uint32_t k1b, uint32_t k2a, uint32_t k2b)
{
  __shared__ ushortT Xs[64*96];
  __shared__ ushortT H1s[64*256];
  int tid=threadIdx.x, lane=tid&63, wv=tid>>6, quad=lane>>4, nl=lane&15;
  int r0 = blockIdx.x*64;
  for (int i=tid; i<64*96; i+=256){
    int rr=i/96, k=i-rr*96; int row=r0+rr; int s=row>>5, b=row&31;
    float v=0.f;
    if (k<80 && s>0) v = dec_inp[((size_t)b*80+k)*500 + (s-1)];
    Xs[i]=f2bf(v);
  }
  __syncthreads();
  f4v acc[4][4];
  #pragma unroll
  for (int mt=0;mt<4;++mt)
    #pragma unroll
    for (int nt=0;nt<4;++nt) acc[mt][nt]=(f4v){0,0,0,0};
  for (int kb=0;kb<3;++kb){
    int c0 = kb*32 + quad*8;
    s8v a[4];
    #pragma unroll
    for (int mt=0;mt<4;++mt) a[mt]=*(const s8v*)(Xs + (mt*16+nl)*96 + c0);
    #pragma unroll
    for (int nt=0;nt<4;++nt){
      int rown = wv*64+nt*16+nl;
      s8v bb;
      if (c0 < 80) bb = pack8(w1 + (size_t)rown*80 + c0);
      else { s8v z={0,0,0,0,0,0,0,0}; bb=z; }
      #pragma unroll
      for (int mt=0;mt<4;++mt) acc[mt][nt]=mfma16(a[mt],bb,acc[mt][nt]);
    }
  }
  #pragma unroll
  for (int mt=0;mt<4;++mt)
    #pragma unroll
    for (int nt=0;nt<4;++nt)
      #pragma unroll
      for (int r=0;r<4;++r){
        int mloc = mt*16+quad*4+r;
        int col  = wv*64+nt*16+nl;
        float v = acc[mt][nt][r]; v = v>0.f? v:0.f;
        uint32_t fidx = (uint32_t)(r0+mloc)*256u + (uint32_t)col;
        v = (part_unif(k1a,k1b,fidx) < 0.5f) ? v*2.0f : 0.0f;
        H1s[mloc*256+col]=f2bf(v);
      }
  __syncthreads();
  #pragma unroll
  for (int mt=0;mt<4;++mt)
    #pragma unroll
    for (int nt=0;nt<4;++nt) acc[mt][nt]=(f4v){0,0,0,0};
  for (int kb=0;kb<8;++kb){
    int c0 = kb*32 + quad*8;
    s8v a[4];
    #pragma unroll
    for (int mt=0;mt<4;++mt) a[mt]=*(const s8v*)(H1s + (mt*16+nl)*256 + c0);
    #pragma unroll
    for (int nt=0;nt<4;++nt){
      int rown = wv*64+nt*16+nl;
      s8v bb = pack8(w2 + (size_t)rown*256 + c0);
      #pragma unroll
      for (int mt=0;mt<4;++mt) acc[mt][nt]=mfma16(a[mt],bb,acc[mt][nt]);
    }
  }
  #pragma unroll
  for (int mt=0;mt<4;++mt)
    #pragma unroll
    for (int nt=0;nt<4;++nt)
      #pragma unroll
      for (int r=0;r<4;++r){
        int mloc = mt*16+quad*4+r;
        int col  = wv*64+nt*16+nl;
        float v = acc[mt][nt][r]; v = v>0.f? v:0.f;
        uint32_t fidx = (uint32_t)(r0+mloc)*256u + (uint32_t)col;
        v = (part_unif(k2a,k2b,fidx) < 0.5f) ? v*2.0f : 0.0f;
        preo[(size_t)(r0+mloc)*256+col]=f2bf(v);
      }
}

// ---------------- processed_memory (bf16 out) ----------------
__global__ __launch_bounds__(256) void k_pm(
  const float* __restrict__ memory, const float* __restrict__ mw, ushortT* __restrict__ pmB)
{
  int row = blockIdx.x*2 + (threadIdx.x>>7);
  int col = threadIdx.x & 127;
  const float* mr = memory + (size_t)row*512;
  const float* wr = mw + (size_t)col*512;
  float acc=0.f;
  for (int k=0;k<512;k+=4){
    float4 a=*(const float4*)(mr+k), b=*(const float4*)(wr+k);
    acc += a.x*b.x + a.y*b.y + a.z*b.z + a.w*b.w;
  }
  pmB[(size_t)row*128+col]=f2bf(acc);
}

// ---------------- phase: attention LSTM (64 WGs) + pq partials ----------------
__device__ __forceinline__ void phaseA(SmemA* L, int t, int ablk, int tid,
  const ushortT* Wai, const ushortT* Wah, const float* abih, const float* abhh,
  const ushortT* preo, const ushortT* AHp, ushortT* AHn, const ushortT* CTX,
  float* ac, float* pq, const ushortT* qwB, uint32_t k3a, uint32_t k3b)
{
  int lane=tid&63, wv=tid>>6, quad=lane>>4, nl=lane&15;
  int ub = ablk*16;
  // stage state into LDS via coherent u64 loads (padded rows: +16B kills 16-way bank conflicts)
  for (int i=tid;i<8192;i+=256){ int r=i>>8, c=i&255;
    *((uint64_t*)(L->stA + r*1032) + c) = ld_u64c((const uint64_t*)(AHp + r*1024) + c); }
  for (int i=tid;i<4096;i+=256){ int r=i>>7, c=i&127;
    *((uint64_t*)(L->stC + r*520) + c) = ld_u64c((const uint64_t*)(CTX + r*512) + c); }
  __syncthreads();
  int rown = wv*1024 + ub + nl;
  const ushortT* bh = Wah + (size_t)rown*1024 + quad*8;
  const ushortT* bx = Wai + (size_t)rown*768  + quad*8;
  const ushortT* a0 = L->stA + nl*1032 + quad*8;  const ushortT* a1 = a0 + 16*1032;
  const ushortT* c0p= L->stC + nl*520  + quad*8;  const ushortT* c1p= c0p + 16*520;
  const ushortT* p0 = preo + ((size_t)t*32 + nl)*256 + quad*8; const ushortT* p1 = p0 + 16*256;
  f4v acc0={0,0,0,0}, acc1={0,0,0,0};
  for (int kb=0;kb<32;++kb){ s8v bb=*(const s8v*)(bh+kb*32);
    acc0=mfma16(*(const s8v*)(a0+kb*32),bb,acc0); acc1=mfma16(*(const s8v*)(a1+kb*32),bb,acc1); }
  for (int kb=0;kb<8;++kb){ s8v bb=*(const s8v*)(bx+kb*32);
    acc0=mfma16(*(const s8v*)(p0+kb*32),bb,acc0); acc1=mfma16(*(const s8v*)(p1+kb*32),bb,acc1); }
  for (int kb=0;kb<16;++kb){ s8v bb=*(const s8v*)(bx+256+kb*32);
    acc0=mfma16(*(const s8v*)(c0p+kb*32),bb,acc0); acc1=mfma16(*(const s8v*)(c1p+kb*32),bb,acc1); }
  #pragma unroll
  for (int r=0;r<4;++r){ L->gbuf[wv][quad*4+r][nl]=acc0[r]; L->gbuf[wv][quad*4+r+16][nl]=acc1[r]; }
  __syncthreads();
  for (int idx=tid; idx<512; idx+=256){
    int b=idx&31, ul=idx>>5; int u=ub+ul;
    float gi=L->gbuf[0][b][ul]+abih[u]       +abhh[u];
    float gf=L->gbuf[1][b][ul]+abih[1024+u]  +abhh[1024+u];
    float gg=L->gbuf[2][b][ul]+abih[2048+u]  +abhh[2048+u];
    float go=L->gbuf[3][b][ul]+abih[3072+u]  +abhh[3072+u];
    float cp=ac[b*1024+u];
    float c2=sigm(gf)*cp + sigm(gi)*tanhf(gg);
    float h =sigm(go)*tanhf(c2);
    uint32_t fidx=((uint32_t)(t*32+b))*1024u+(uint32_t)u;
    h = (part_unif(k3a,k3b,fidx) < 0.9f) ? h*(1.0f/0.9f) : 0.0f;
    ac[b*1024+u]=c2;
    L->ahs[b*17+ul]=h;
  }
  __syncthreads();
  // packed coherent AH store (4 bf16 per u64) + qw slice staging
  if (tid<128){
    int b=tid>>2, j=tid&3;
    uint32_t v0 = (uint32_t)f2bf(L->ahs[b*17+4*j+0]) | ((uint32_t)f2bf(L->ahs[b*17+4*j+1])<<16);
    uint32_t v1 = (uint32_t)f2bf(L->ahs[b*17+4*j+2]) | ((uint32_t)f2bf(L->ahs[b*17+4*j+3])<<16);
    st_u64c((uint64_t*)(AHn + b*1024 + ub) + j, (uint64_t)v0 | ((uint64_t)v1<<32));
  }
  for (int i=tid;i<2048;i+=256){ int a=i>>4,u=i&15; L->qsl[a*17+u]=bf2f(qwB[(size_t)a*1024+ub+u]); }
  __syncthreads();
  int b=tid&31, ag=tid>>5;
  for (int j=0;j<16;++j){
    int a=ag*16+j;
    float s=0.f;
    #pragma unroll
    for (int u=0;u<16;++u) s += L->ahs[b*17+u]*L->qsl[a*17+u];
    atomicAdd(&pq[b*128+a], s);
  }
}

// ---------------- phase: decoder LSTM (64 WGs) ----------------
__device__ __forceinline__ void phaseC(SmemC* L, int t, int cblk, int tid,
  const ushortT* Wdi, const ushortT* Wdh, const float* dbih, const float* dbhh,
  const ushortT* AHc, const ushortT* CTX, const ushortT* DHp, ushortT* DHn,
  float* dc, uint32_t k4a, uint32_t k4b)
{
  int lane=tid&63, wv=tid>>6, quad=lane>>4, nl=lane&15;
  int ub = cblk*16;
  for (int i=tid;i<8192;i+=256){ int r=i>>8, c=i&255;
    *((uint64_t*)(L->stA + r*1032) + c) = ld_u64c((const uint64_t*)(AHc + r*1024) + c); }
  for (int i=tid;i<8192;i+=256){ int r=i>>8, c=i&255;
    *((uint64_t*)(L->stD + r*1032) + c) = ld_u64c((const uint64_t*)(DHp + r*1024) + c); }
  __syncthreads();
  int rown = wv*1024 + ub + nl;
  const ushortT* bh = Wdh + (size_t)rown*1024 + quad*8;
  const ushortT* bx = Wdi + (size_t)rown*1536 + quad*8;
  const ushortT* a0 = L->stA + nl*1032 + quad*8;  const ushortT* a1 = a0 + 16*1032;
  const ushortT* d0 = L->stD + nl*1032 + quad*8;  const ushortT* d1 = d0 + 16*1032;
  const ushortT* c0g= CTX + (size_t)nl*512 + quad*8;  const ushortT* c1g= c0g + 16*512;
  f4v acc0={0,0,0,0}, acc1={0,0,0,0};
  for (int kb=0;kb<32;++kb){ s8v bb=*(const s8v*)(bx+kb*32);
    acc0=mfma16(*(const s8v*)(a0+kb*32),bb,acc0); acc1=mfma16(*(const s8v*)(a1+kb*32),bb,acc1); }
  for (int kb=0;kb<16;++kb){ s8v bb=*(const s8v*)(bx+1024+kb*32);
    acc0=mfma16(ld16c(c0g+kb*32),bb,acc0); acc1=mfma16(ld16c(c1g+kb*32),bb,acc1); }
  for (int kb=0;kb<32;++kb){ s8v bb=*(const s8v*)(bh+kb*32);
    acc0=mfma16(*(const s8v*)(d0+kb*32),bb,acc0); acc1=mfma16(*(const s8v*)(d1+kb*32),bb,acc1); }
  #pragma unroll
  for (int r=0;r<4;++r){ L->gbuf[wv][quad*4+r][nl]=acc0[r]; L->gbuf[wv][quad*4+r+16][nl]=acc1[r]; }
  __syncthreads();
  for (int idx=tid; idx<512; idx+=256){
    int b=idx&31, ul=idx>>5; int u=ub+ul;
    float gi=L->gbuf[0][b][ul]+dbih[u]      +dbhh[u];
    float gf=L->gbuf[1][b][ul]+dbih[1024+u] +dbhh[1024+u];
    float gg=L->gbuf[2][b][ul]+dbih[2048+u] +dbhh[2048+u];
    float go=L->gbuf[3][b][ul]+dbih[3072+u] +dbhh[3072+u];
    float cp=dc[b*1024+u];
    float c2=sigm(gf)*cp + sigm(gi)*tanhf(gg);
    float h =sigm(go)*tanhf(c2);
    uint32_t fidx=((uint32_t)(t*32+b))*1024u+(uint32_t)u;
    h = (part_unif(k4a,k4b,fidx) < 0.9f) ? h*(1.0f/0.9f) : 0.0f;
    dc[b*1024+u]=c2;
    L->dhs[b*17+ul]=h;
  }
  __syncthreads();
  if (tid<128){
    int b=tid>>2, j=tid&3;
    uint32_t v0 = (uint32_t)f2bf(L->dhs[b*17+4*j+0]) | ((uint32_t)f2bf(L->dhs[b*17+4*j+1])<<16);
    uint32_t v1 = (uint32_t)f2bf(L->dhs[b*17+4*j+2]) | ((uint32_t)f2bf(L->dhs[b*17+4*j+3])<<16);
    st_u64c((uint64_t*)(DHn + b*1024 + ub) + j, (uint64_t)v0 | ((uint64_t)v1<<32));
  }
}

// ---------------- phase: projection of step td (6 WGs) ----------------
__device__ __forceinline__ void phaseProj(SmemPj* P, int td, int wgd, int tid,
  const ushortT* Wpg, const float* pjb, const float* gb,
  const ushortT* DHd, const ushortT* CTX, float* out_mel, float* out_gate)
{
  int lane=tid&63, wv=tid>>6, quad=lane>>4, nl=lane&15;
  int rb = wgd*16;
  int mt = wv&1, kh = wv>>1;
  int mrow = nl + mt*16;
  const ushortT* br  = Wpg + (size_t)(rb+nl)*1536 + quad*8;
  const ushortT* dhp = DHd + (size_t)mrow*1024 + quad*8;
  const ushortT* cxp = CTX + (size_t)mrow*512  + quad*8;
  f4v acc={0,0,0,0};
  for (int kb=0;kb<24;++kb){
    int kk = kh*768 + kb*32;
    s8v aa = (kk < 1024) ? ld16c(dhp + kk) : ld16c(cxp + (kk-1024));
    s8v bb = *(const s8v*)(br + kk);
    acc = mfma16(aa,bb,acc);
  }
  #pragma unroll
  for (int r=0;r<4;++r) P->dsum[kh][mt*16+quad*4+r][nl]=acc[r];
  __syncthreads();
  for (int idx=tid; idx<512; idx+=256){
    int m=idx>>4, n=idx&15;
    float v = P->dsum[0][m][n] + P->dsum[1][m][n];
    int r = rb + n;
    if (r < 80){
      v += pjb[r];
      out_mel[(size_t)(m*80+r)*500 + td] = v;
    } else if (r == 80){
      v += gb[0];
      out_gate[(size_t)m*500 + td] = v;
    }
  }
}

// ---------------- phase: location conv + energies (128 WGs) ----------------
__device__ __forceinline__ void phaseB1(SmemB1* S, int t, int blk, int tid,
  const float* lcw, const float* llw, const float* vw,
  const float* aw, const float* awc, const ushortT* pmB, const float* pq,
  const int* mlen, float* ebuf)
{
  int b=blk>>2, ch=blk&3; int t0=ch*100;
  for (int i=tid;i<130;i+=256){
    int tt=t0-15+i; float a=0.f,c=0.f;
    if (tt>=0 && tt<TIN){ a=ld_f32c(aw + b*TIN+tt); c=ld_f32c(awc + b*TIN+tt); }
    S->awp[i]=a; S->awcp[i]=c;
  }
  for (int i=tid;i<992;i+=256){
    int f=i/31, j=i-f*31;
    S->cw0[i]=lcw[(f*2+0)*31+j];
    S->cw1[i]=lcw[(f*2+1)*31+j];
  }
  for (int i=tid;i<4096;i+=256){ int a=i>>5,f=i&31; S->lw[a*33+f]=llw[i]; }
  if (tid<128){ S->vv[tid]=vw[tid]; S->pqv[tid]=ld_f32c(pq + b*128+tid); }
  __syncthreads();
  for (int it=tid; it<3200; it+=256){
    int tl=it>>5, f=it&31;
    const float* c0=S->cw0+f*31; const float* c1=S->cw1+f*31;
    float s=0.f;
    #pragma unroll
    for (int j=0;j<31;++j) s += S->awp[tl+j]*c0[j] + S->awcp[tl+j]*c1[j];
    S->locl[tl*32+f]=s;
  }
  __syncthreads();
  {
    int a=tid&127, g=tid>>7, wid=tid>>6;
    const float* lwa = S->lw + a*33;
    for (int tl=g; tl<100; tl+=2){
      const float* lt = S->locl + tl*32;
      float l2=0.f;
      #pragma unroll
      for (int f=0;f<32;++f) l2 += lt[f]*lwa[f];
      float x = S->pqv[a] + l2 + bf2f(pmB[((size_t)b*TIN + (t0+tl))*128 + a]);
      float cv = S->vv[a]*tanhf(x);
      #pragma unroll
      for (int o=32;o>0;o>>=1) cv += __shfl_xor(cv,o);
      if ((tid&63)==0) S->epart[tl*2+(wid&1)]=cv;
    }
  }
  __syncthreads();
  if (tid<100){
    int tg=t0+tid;
    float e = S->epart[tid*2]+S->epart[tid*2+1];
    if (tg >= mlen[b]) e = -__builtin_inff();
    st_f32c(ebuf + b*TIN+tg, e);
  }
}

// ---------------- phase: softmax + context quarter (128 WGs) ----------------
__device__ __forceinline__ void phaseB2(SmemB2* S, int t, int blk, int tid,
  const float* ebuf, const ushortT* memB,
  float* aw, float* awc, ushortT* CTX, float* out_align)
{
  int b=blk>>2, q=blk&3, wid=tid>>6;
  float lm = -__builtin_inff();
  for (int i=tid;i<400;i+=256){ float v=ld_f32c(ebuf + b*TIN+i); S->p[i]=v; lm=fmaxf(lm,v); }
  #pragma unroll
  for (int o=32;o>0;o>>=1) lm=fmaxf(lm,__shfl_xor(lm,o));
  if ((tid&63)==0) S->red[wid]=lm;
  __syncthreads();
  float mx = fmaxf(fmaxf(S->red[0],S->red[1]),fmaxf(S->red[2],S->red[3]));
  if (!(mx > -__builtin_inff())) mx = 0.f;
  float ls=0.f;
  for (int i=tid;i<400;i+=256){ float pe=__expf(S->p[i]-mx); S->p[i]=pe; ls+=pe; }
  #pragma unroll
  for (int o=32;o>0;o>>=1) ls += __shfl_xor(ls,o);
  if ((tid&63)==0) S->red[4+wid]=ls;
  __syncthreads();
  float Ssum = S->red[4]+S->red[5]+S->red[6]+S->red[7];
  float rS = (Ssum>0.f) ? 1.0f/Ssum : 0.f;
  for (int i=tid;i<400;i+=256){
    float a2 = S->p[i]*rS; S->p[i]=a2;
    if (q==0){
      st_f32c(aw + b*TIN+i, a2);
      st_f32c(awc + b*TIN+i, ld_f32c(awc + b*TIN+i) + a2);
      out_align[((size_t)b*500 + t)*400 + i]=a2;
    }
  }
  __syncthreads();
  int dl = tid&127, th = tid>>7;
  int d = q*128 + dl;
  const ushortT* mb = memB + (size_t)b*TIN*512 + d;
  float c=0.f;
  for (int tt=th*200; tt<th*200+200; ++tt) c += S->p[tt]*bf2f(mb[(size_t)tt*512]);
  S->part[tid]=c;
  __syncthreads();
  if (tid<32){
    uint32_t v0 = (uint32_t)f2bf(S->part[4*tid+0]+S->part[4*tid+128]) |
                  ((uint32_t)f2bf(S->part[4*tid+1]+S->part[4*tid+129])<<16);
    uint32_t v1 = (uint32_t)f2bf(S->part[4*tid+2]+S->part[4*tid+130]) |
                  ((uint32_t)f2bf(S->part[4*tid+3]+S->part[4*tid+131])<<16);
    st_u64c((uint64_t*)(CTX + b*512 + q*128) + tid, (uint64_t)v0 | ((uint64_t)v1<<32));
  }
}

// ---------------- the persistent loop kernel ----------------
__global__ __launch_bounds__(256,1) void k_loop(
  const ushortT* __restrict__ Wai, const ushortT* __restrict__ Wah,
  const float* __restrict__ abih, const float* __restrict__ abhh,
  const ushortT* __restrict__ Wdi, const ushortT* __restrict__ Wdh,
  const float* __restrict__ dbih, const float* __restrict__ dbhh,
  const ushortT* __restrict__ Wpg, const float* __restrict__ pjb, const float* __restrict__ gb,
  const ushortT* __restrict__ preo, const ushortT* __restrict__ qwB,
  const ushortT* __restrict__ pmB, const ushortT* __restrict__ memB,
  const float* __restrict__ lcw, const float* __restrict__ llw, const float* __restrict__ vw,
  const int* __restrict__ mlen,
  ushortT* __restrict__ AH0, ushortT* __restrict__ AH1,
  ushortT* __restrict__ DH0, ushortT* __restrict__ DH1,
  ushortT* __restrict__ CTX,
  float* __restrict__ ac, float* __restrict__ dc,
  float* __restrict__ aw, float* __restrict__ awc,
  float* __restrict__ ebuf, float* __restrict__ pq,
  float* __restrict__ out_mel, float* __restrict__ out_gate, float* __restrict__ out_align,
  int* __restrict__ bar,
  uint32_t k3a, uint32_t k3b, uint32_t k4a, uint32_t k4b)
{
  extern __shared__ char smem_raw[];
  SmemU* sm = (SmemU*)smem_raw;
  int blk=blockIdx.x, tid=threadIdx.x;
  int nb=0;
  // A(0): reads AH1 (zeros), CTX (zeros); writes AH0, pq partials
  if (blk>=128 && blk<192)
    phaseA(&sm->a, 0, blk-128, tid, Wai, Wah, abih, abhh, preo, AH1, AH0, CTX, ac, pq, qwB, k3a, k3b);
  gridbar(bar, (++nb)*NBLK);
  for (int t=0; t<TOUT; ++t){
    const ushortT* AHc = (t&1)? AH1 : AH0;       // ah(t)
    ushortT* AHn = (t&1)? AH0 : AH1;             // ah(t+1) dest
    const ushortT* DHp = (t&1)? DH0 : DH1;       // dh(t-1)
    ushortT* DHn = (t&1)? DH1 : DH0;             // dh(t) dest
    // ---- phase 1: B1(t) on 0..127; proj(t-1) on 128..133 ----
    if (blk<128)
      phaseB1(&sm->b1, t, blk, tid, lcw, llw, vw, aw, awc, pmB, pq, mlen, ebuf);
    else if (blk<134 && t>0)
      phaseProj(&sm->pj, t-1, blk-128, tid, Wpg, pjb, gb, DHp, CTX, out_mel, out_gate);
    gridbar(bar, (++nb)*NBLK);
    // ---- phase 2: B2(t) on 0..127; pq-zero on 128 ----
    if (blk<128)
      phaseB2(&sm->b2, t, blk, tid, ebuf, memB, aw, awc, CTX, out_align);
    else if (blk==128){
      for (int i=tid;i<2048;i+=256) st_u64c((uint64_t*)pq + i, 0ull);
    }
    gridbar(bar, (++nb)*NBLK);
    // ---- phase 3: C(t) on 0..63; A(t+1) on 128..191 ----
    if (blk<64)
      phaseC(&sm->c, t, blk, tid, Wdi, Wdh, dbih, dbhh, AHc, CTX, DHp, DHn, dc, k4a, k4b);
    else if (blk>=128 && blk<192 && t+1<TOUT)
      phaseA(&sm->a, t+1, blk-128, tid, Wai, Wah, abih, abhh, preo, AHc, AHn, CTX, ac, pq, qwB, k3a, k3b);
    gridbar(bar, (++nb)*NBLK);
  }
  // final projection of step 499 (dh(499)=DH1, ctx(499)=CTX)
  if (blk>=128 && blk<134)
    phaseProj(&sm->pj, TOUT-1, blk-128, tid, Wpg, pjb, gb, DH1, CTX, out_mel, out_gate);
}

// ---------------- host ----------------
extern "C" void kernel_launch(void* const* d_in, const int* in_sizes, int n_in,
                              void* d_out, int out_size, void* d_ws, size_t ws_size,
                              hipStream_t stream) {
  (void)in_sizes; (void)n_in; (void)out_size; (void)ws_size;
  const float* memory  = (const float*)d_in[0];
  const float* dec_inp = (const float*)d_in[1];
  const int*   mlen    = (const int*)d_in[2];
  const float* pw1     = (const float*)d_in[3];
  const float* pw2     = (const float*)d_in[4];
  const float* awih    = (const float*)d_in[5];
  const float* awhh    = (const float*)d_in[6];
  const float* abih    = (const float*)d_in[7];
  const float* abhh    = (const float*)d_in[8];
  const float* qw      = (const float*)d_in[9];
  const float* mw      = (const float*)d_in[10];
  const float* vw      = (const float*)d_in[11];
  const float* lcw     = (const float*)d_in[12];
  const float* llw     = (const float*)d_in[13];
  const float* dwih    = (const float*)d_in[14];
  const float* dwhh    = (const float*)d_in[15];
  const float* dbih    = (const float*)d_in[16];
  const float* dbhh    = (const float*)d_in[17];
  const float* pjw     = (const float*)d_in[18];
  const float* pjb     = (const float*)d_in[19];
  const float* gw      = (const float*)d_in[20];
  const float* gb      = (const float*)d_in[21];

  char* w = (char*)d_ws;
  size_t off=0;
  auto alloc = [&](size_t n)->char*{ char* p=w+off; off=(off+n+255)&~(size_t)255; return p; };
  ushortT* Wai = (ushortT*)alloc(4096UL*768*2);
  ushortT* Wah = (ushortT*)alloc(4096UL*1024*2);
  ushortT* Wdi = (ushortT*)alloc(4096UL*1536*2);
  ushortT* Wdh = (ushortT*)alloc(4096UL*1024*2);
  ushortT* Wpg = (ushortT*)alloc(96UL*1536*2);
  ushortT* preo= (ushortT*)alloc(16000UL*256*2);
  ushortT* pmB = (ushortT*)alloc(12800UL*128*2);
  ushortT* memB= (ushortT*)alloc(32UL*400*512*2);
  ushortT* qwB = (ushortT*)alloc(128UL*1024*2);
  ushortT* AH0 = (ushortT*)alloc(32UL*1024*2);
  ushortT* AH1 = (ushortT*)alloc(32UL*1024*2);
  ushortT* DH0 = (ushortT*)alloc(32UL*1024*2);
  ushortT* DH1 = (ushortT*)alloc(32UL*1024*2);
  ushortT* CTX = (ushortT*)alloc(32UL*512*2);
  float*   ac  = (float*)alloc(32UL*1024*4);
  float*   dc  = (float*)alloc(32UL*1024*4);
  float*   aw  = (float*)alloc(12800UL*4);
  float*   awc = (float*)alloc(12800UL*4);
  float*   ebuf= (float*)alloc(12800UL*4);
  float*   pq  = (float*)alloc(4096UL*4);
  int*     bar = (int*)alloc(256);

  // JAX partitionable split(key(42), 4): subkey_i = threefry((0,42), (0, i))
  uint32_t K[4][2];
  for (uint32_t i=0;i<4;++i) tf2x32(0u,42u,0u,i,&K[i][0],&K[i][1]);

  float* out_mel   = (float*)d_out;
  float* out_gate  = out_mel + 1280000;
  float* out_align = out_mel + 1296000;

  k_setup<<<1024,256,0,stream>>>(awih,awhh,dwih,dwhh,pjw,gw,memory,qw,
                                 Wai,Wah,Wdi,Wdh,Wpg,memB,qwB,
                                 AH0,AH1,DH0,DH1,CTX,ac,dc,aw,awc,pq,bar);
  k_prenet<<<250,256,0,stream>>>(dec_inp, pw1, pw2, preo, K[0][0],K[0][1], K[1][0],K[1][1]);
  k_pm<<<6400,256,0,stream>>>(memory, mw, pmB);
  static bool attr_set = false;
  if (!attr_set){
    hipFuncSetAttribute((const void*)k_loop, hipFuncAttributeMaxDynamicSharedMemorySize,
                        (int)sizeof(SmemU));
    attr_set = true;
  }
  k_loop<<<NBLK,256,sizeof(SmemU),stream>>>(Wai,Wah,abih,abhh,Wdi,Wdh,dbih,dbhh,Wpg,pjb,gb,
                               preo,qwB,pmB,memB,lcw,llw,vw,mlen,
                               AH0,AH1,DH0,DH1,CTX,ac,dc,aw,awc,ebuf,pq,
                               out_mel,out_gate,out_align,bar,
                               K[2][0],K[2][1],K[3][0],K[3][1]);
}